// Round 9
// baseline (486.074 us; speedup 1.0000x reference)
//
#include <hip/hip_runtime.h>
#include <math.h>
#include <stdint.h>

// B=4, N=1024, D=1024, H=16, DH=64, MLP=4096. Inputs fp32, output fp32.
// Round 18: r8 counters: FF2 60us top, conflicts=0 (swizzle verified),
// MfmaUtil 22 / VALU 18 / HBM 14 / occ 19.6% -> LDS-BW + barrier-bound at
// wave tile 64x32 (21.3 FLOP/LDS-B) and 2 blk/CU.
// (1) FF2 split-K=4: tile 128x128 (wave 64x64, ratio 32), BK=32 (32KB LDS),
//     grid (32,8,4)=1024 -> 4 blk/CU; fp32 atomicAdd onto memset h2F;
//     b2 folded into final ln_res (ADDB).
// (2) kcT fused into qc|kc epilogue (WT scatter, aligned 8B stores);
//     transpose_cast dispatch removed. 14 dispatches + 1 memset.
typedef unsigned short u16;
typedef u16   u16x4 __attribute__((ext_vector_type(4)));
typedef u16   u16x8 __attribute__((ext_vector_type(8)));
typedef __bf16 bf16x8 __attribute__((ext_vector_type(8)));
typedef float  f32x4 __attribute__((ext_vector_type(4)));

#define B_   4
#define N_   1024
#define D_   1024
#define MLP_ 4096

__device__ __forceinline__ float bf2f(u16 v) {
    unsigned u = ((unsigned)v) << 16;
    return __builtin_bit_cast(float, u);
}
__device__ __forceinline__ u16 f2bf(float f) {
    unsigned u = __builtin_bit_cast(unsigned, f);
    u += 0x7fff + ((u >> 16) & 1);   // RN-even
    return (u16)(u >> 16);
}
__device__ __forceinline__ bf16x8 ld8(const u16* p) {
    return __builtin_bit_cast(bf16x8, *(const u16x8*)p);
}
// async 16B global -> LDS (lds dest = wave-uniform base + lane*16)
__device__ __forceinline__ void gll16(const u16* g, u16* l) {
    __builtin_amdgcn_global_load_lds(
        (const __attribute__((address_space(1))) unsigned int*)g,
        (__attribute__((address_space(3))) unsigned int*)l,
        16, 0, 0);
}
// GELU(v) = 0.5 v (1 + erf(v/sqrt2)); erf via A&S 7.1.26 (|err|<1.5e-7).
__device__ __forceinline__ float gelu_f(float v) {
    float xs = v * 0.70710678118654752f;     // erf argument
    float ax = fabsf(xs);
    float t  = __builtin_amdgcn_rcpf(fmaf(0.3275911f, ax, 1.0f));
    float p  = fmaf(1.061405429f, t, -1.453152027f);
    p = fmaf(p, t, 1.421413741f);
    p = fmaf(p, t, -0.284496736f);
    p = fmaf(p, t, 0.254829592f);
    p *= t;
    float e = __expf(-ax * ax);
    float er = 1.0f - p * e;                 // erf(|xs|)
    er = copysignf(er, xs);
    return 0.5f * v * (1.0f + er);
}

// ---------------------------------------------------------------------------
// Fused prep: blocks [0,4096) convert x|enc fp32->bf16 (8 elems/thread);
// blocks [4096,10240) do the six 1024x1024 weight transposes (fp32->bf16).
// ---------------------------------------------------------------------------
__global__ __launch_bounds__(256)
void prep_all(const float* __restrict__ x, const float* __restrict__ enc,
              u16* __restrict__ xB, u16* __restrict__ encB,
              const float* __restrict__ p0, const float* __restrict__ p1,
              const float* __restrict__ p2, const float* __restrict__ p3,
              const float* __restrict__ p4, const float* __restrict__ p5,
              u16* __restrict__ Wsa, u16* __restrict__ Wca)
{
    __shared__ u16 tile[32][33];
    int bid = blockIdx.x;
    if (bid < 4096) {
        // ---- convert role ----
        const float* in = x; u16* out = xB;
        if (bid >= 2048) { in = enc; out = encB; bid -= 2048; }
        long i = (long)bid * 256 + threadIdx.x;        // < 524288 exactly
        f32x4 a = *(const f32x4*)&in[i * 8];
        f32x4 b = *(const f32x4*)&in[i * 8 + 4];
        u16x8 h;
        h[0] = f2bf(a[0]); h[1] = f2bf(a[1]); h[2] = f2bf(a[2]); h[3] = f2bf(a[3]);
        h[4] = f2bf(b[0]); h[5] = f2bf(b[1]); h[6] = f2bf(b[2]); h[7] = f2bf(b[3]);
        *(u16x8*)&out[i * 8] = h;
        return;
    }
    // ---- weight-transpose role ----
    int sub = bid - 4096;
    const int z = sub >> 10;          // 0..5
    const int t2 = sub & 1023;
    const int bx = (t2 & 31) * 32, by = (t2 >> 5) * 32;
    const float* in = p0;
    if (z == 1) in = p1;
    else if (z == 2) in = p2;
    else if (z == 3) in = p3;
    else if (z == 4) in = p4;
    else if (z == 5) in = p5;
    u16* out = (z < 3) ? Wsa + (long)z * (1 << 20) : Wca + (long)(z - 3) * (1 << 20);
    const int tx = threadIdx.x & 31, ty = threadIdx.x >> 5;
#pragma unroll
    for (int i = ty; i < 32; i += 8)
        tile[i][tx] = f2bf(in[(long)(by + i) * 1024 + bx + tx]);
    __syncthreads();
#pragma unroll
    for (int i = ty; i < 32; i += 8)
        out[(long)(bx + i) * 1024 + by + tx] = tile[tx][i];
}

// ---------------------------------------------------------------------------
// GEMM body: C[m,n] = scale*sum_k A[m,k]*Bt[n,k] (+bias)(gelu). A,Bt bf16.
// Tile TM x TN x BK, 4 waves (2x2 of TM/2 x TN/2), 16x16x32 bf16 MFMA,
// global_load_lds width=16, double-buffered K-loop (1 barrier per BK).
// T2 swizzle: LDS slot(c, r) = c ^ (r & CMASK) per 16B chunk (rule #21).
// ATOMIC: fp32 atomicAdd epilogue (split-K). WT: also scatter-write C^T
// (per-1024-row-batch) to CT as aligned 8B stores.
// ---------------------------------------------------------------------------
template<int TM, int TN, int BK, int OUTF32, int BIAS, int GELU, int ATOMIC, int WT>
__device__ __forceinline__ void gemm_body(
    const u16* __restrict__ A, const u16* __restrict__ Bt, char* __restrict__ Cp,
    const float* __restrict__ bias, u16* __restrict__ CT, float scale, int K,
    int lda, int ldb, int ldc, int m0, int n0)
{
    constexpr int MT = TM / 32, NT = TN / 32;   // frag tiles per wave
    constexpr int CPT = BK / 8;                 // 16B chunks per LDS row
    constexpr int RPP = 2048 / BK;              // rows staged per 256-thread pass
    constexpr int CMASK = (CPT - 1) & 7;        // swizzle mask (BK=64 -> 7, BK=32 -> 3)
    __shared__ alignas(16) u16 As[2][TM * BK];
    __shared__ alignas(16) u16 Bs[2][TN * BK];
    const int t = threadIdx.x, lane = t & 63, w = t >> 6;
    const int wr = (w >> 1) * (TM / 2), wc = (w & 1) * (TN / 2);
    const int fr = lane & 15, fq = lane >> 4;
    f32x4 acc[MT][NT] = {};

    // staging: 256 threads x 16B = 4KB per pass (RPP rows x BK cols).
    const int r0a = t / CPT;
    const int c0sw = ((t % CPT) ^ (r0a & CMASK)) * 8;
    auto stageA = [&](u16* dst, int k0) {
#pragma unroll
        for (int p = 0; p < TM / RPP; p++)
            gll16(A + (long)(m0 + p * RPP + r0a) * lda + k0 + c0sw, dst + p * 2048 + w * 512);
    };
    auto stageB = [&](u16* dst, int k0) {
#pragma unroll
        for (int p = 0; p < TN / RPP; p++)
            gll16(Bt + (long)(n0 + p * RPP + r0a) * ldb + k0 + c0sw, dst + p * 2048 + w * 512);
    };

    stageA(As[0], 0);
    stageB(Bs[0], 0);
    int cur = 0;
    for (int k0 = 0; k0 < K; k0 += BK) {
        __syncthreads();                       // drains vmcnt -> buf[cur] ready
        if (k0 + BK < K) {
            stageA(As[cur ^ 1], k0 + BK);
            stageB(Bs[cur ^ 1], k0 + BK);
        }
        const u16* as = As[cur];
        const u16* bs = Bs[cur];
#pragma unroll
        for (int kk = 0; kk < BK; kk += 32) {
            bf16x8 af[MT], bfv[NT];
#pragma unroll
            for (int mt = 0; mt < MT; mt++) {
                const int row = wr + mt * 16 + fr;
                af[mt] = ld8(&as[row * BK + ((((kk >> 3) + fq) ^ (row & CMASK)) << 3)]);
            }
#pragma unroll
            for (int nt = 0; nt < NT; nt++) {
                const int row = wc + nt * 16 + fr;
                bfv[nt] = ld8(&bs[row * BK + ((((kk >> 3) + fq) ^ (row & CMASK)) << 3)]);
            }
#pragma unroll
            for (int mt = 0; mt < MT; mt++)
#pragma unroll
                for (int nt = 0; nt < NT; nt++)
                    acc[mt][nt] = __builtin_amdgcn_mfma_f32_16x16x32_bf16(af[mt], bfv[nt], acc[mt][nt], 0, 0, 0);
        }
        cur ^= 1;
    }

    // C/D layout (m89/m91): col = lane&15, row = (lane>>4)*4 + reg.
#pragma unroll
    for (int nt = 0; nt < NT; nt++) {
        const int col = n0 + wc + nt * 16 + fr;
        float bv = 0.f;
        if (BIAS) bv = bias[col];
#pragma unroll
        for (int mt = 0; mt < MT; mt++) {
            const int rbase = m0 + wr + mt * 16 + fq * 4;
            u16 tv[4];
#pragma unroll
            for (int r = 0; r < 4; r++) {
                float v = acc[mt][nt][r] * scale;
                if (BIAS) v += bv;
                if (GELU) v = gelu_f(v);
                long idx = (long)(rbase + r) * ldc + col;
                if (ATOMIC)      atomicAdd((float*)Cp + idx, v);
                else if (OUTF32) ((float*)Cp)[idx] = v;
                else             ((u16*) Cp)[idx] = f2bf(v);
                if (WT) tv[r] = f2bf(v);
            }
            if (WT && CT) {   // transposed write, folded per-1024-row batch
                long tb = ((long)(rbase >> 10)) * 1048576 + (long)col * 1024 + (rbase & 1023);
                *(u16x4*)&CT[tb] = *(const u16x4*)tv;
            }
        }
    }
}

// ---------------------------------------------------------------------------
// General GEMM dispatch wrapper.
// SEL=0: single problem. SEL=1: y-half selects (A0,B0,C0)/(A1,B1,C1),
//        kc-half also scatter-writes CT when WT. SEL=3: z = K-split index
//        (A,Bt advance by z*1024 along k; C shared, ATOMIC accumulate).
// LDS = 4*BK*(TM+TN) bytes. min-waves: 32KB -> 4 blk/CU, 48KB -> 3, 64KB -> 2.
// ---------------------------------------------------------------------------
template<int TM, int TN, int BK, int SEL, int OUTF32, int BIAS, int GELU, int ATOMIC, int WT>
__global__ __launch_bounds__(256, ((TM + TN >= 256) ? ((BK == 64) ? 2 : 4)
                                                    : ((BK == 64) ? 3 : 4)))
void gemm_a(const u16* __restrict__ A0, const u16* __restrict__ A1,
            const u16* __restrict__ B0, const u16* __restrict__ B1,
            void* __restrict__ C0v, void* __restrict__ C1v,
            const float* __restrict__ bias, u16* __restrict__ CT,
            float scale, int K,
            int lda, int ldb, int ldc,
            long sA, long sB, long sC)
{
    int by = blockIdx.y, bz = blockIdx.z;
    const u16* A = A0; const u16* Bt = B0; char* Cp = (char*)C0v;
    u16* CTp = nullptr;
    if (SEL == 1) {
        int half = gridDim.y >> 1;
        if (by >= half) { A = A1; Bt = B1; Cp = (char*)C1v; by -= half; CTp = CT; }
    }
    A += bz * sA;  Bt += bz * sB;  Cp += bz * sC * (OUTF32 ? 4 : 2);
    if (SEL == 3) { A += (long)bz * 1024; Bt += (long)bz * 1024; }
    gemm_body<TM, TN, BK, OUTF32, BIAS, GELU, ATOMIC, WT>(
        A, Bt, Cp, bias, CTp, scale, K, lda, ldb, ldc, blockIdx.x * TM, by * TN);
}

// ---------------------------------------------------------------------------
// Merged q|k|vT|vcT dispatch: 1024 blocks of 128x128, K=1024, BK=32, 4/CU.
//  bid <  512: q|k  (M=4096): bx=bid&31, by=bid>>5; by<8 -> q, else k.
//  bid >= 512: vT|vcT per batch: bx=sub&7, by=(sub>>3)&7, bz=sub>>6;
//              bz<4 -> vT[b]=WsaV x xB[b]^T, else vcT[b]=WcaV x encB[b]^T.
// ---------------------------------------------------------------------------
__global__ __launch_bounds__(256, 4)
void gemm_qkv4(const u16* __restrict__ xB,  const u16* __restrict__ Wq,
               const u16* __restrict__ Wk,  u16* __restrict__ qB,
               u16* __restrict__ kB,
               const u16* __restrict__ Wv,  const u16* __restrict__ Wvc,
               const u16* __restrict__ encB,
               u16* __restrict__ vTB, u16* __restrict__ vcTB)
{
    const long M1 = (long)N_ * D_;
    int bid = blockIdx.x;
    const u16* A; const u16* Bt; u16* C; int m0, n0;
    if (bid < 512) {
        int bx = bid & 31, by = bid >> 5;
        A = xB; m0 = bx * 128;
        if (by < 8) { Bt = Wq; C = qB; n0 = by * 128; }
        else        { Bt = Wk; C = kB; n0 = (by - 8) * 128; }
    } else {
        int sub = bid - 512;
        int bx = sub & 7, by = (sub >> 3) & 7, bz = sub >> 6;
        m0 = bx * 128; n0 = by * 128;
        if (bz < 4) { A = Wv;  Bt = xB   + (long)bz * M1;       C = vTB  + (long)bz * M1; }
        else        { A = Wvc; Bt = encB + (long)(bz - 4) * M1; C = vcTB + (long)(bz - 4) * M1; }
    }
    gemm_body<128, 128, 32, 0, 0, 0, 0, 0>(
        A, Bt, (char*)C, nullptr, nullptr, 1.f, 1024, 1024, 1024, 1024, m0, n0);
}

// ---------------------------------------------------------------------------
// w1 [1024,4096] and w2 [4096,1024] transposes fused: grid (128, 32, 2).
// z=0: direct tiles for w1. z=1: remap (bx,by) -> (bx>>2, by*4 + (bx&3)).
// ---------------------------------------------------------------------------
__global__ __launch_bounds__(256)
void transpose_ff(const float* __restrict__ w1, const float* __restrict__ w2,
                  u16* __restrict__ o1, u16* __restrict__ o2)
{
    __shared__ u16 tile[32][33];
    const float* in; u16* out; int R, C, bx, by;
    if (blockIdx.z == 0) {
        in = w1; out = o1; R = 1024; C = 4096;
        bx = blockIdx.x; by = blockIdx.y;                 // bx<128, by<32
    } else {
        in = w2; out = o2; R = 4096; C = 1024;
        bx = blockIdx.x >> 2; by = blockIdx.y * 4 + (blockIdx.x & 3);  // bx<32, by<128
    }
    const int x0 = bx * 32, y0 = by * 32;
    const int tx = threadIdx.x & 31, ty = threadIdx.x >> 5;
#pragma unroll
    for (int i = ty; i < 32; i += 8)
        tile[i][tx] = f2bf(in[(long)(y0 + i) * C + x0 + tx]);
    __syncthreads();
#pragma unroll
    for (int i = ty; i < 32; i += 8)
        out[(long)(x0 + i) * R + y0 + tx] = tile[tx][i];
}

// ---------------------------------------------------------------------------
// Row softmax: 1024 fp32 in -> 1024 bf16 out; one wave per row.
// Lane owns 16 contiguous cols (f32x4 loads / u16x8 stores).
// ---------------------------------------------------------------------------
__global__ __launch_bounds__(256)
void softmax_1024(const float* __restrict__ in, u16* __restrict__ out)
{
    const int lane = threadIdx.x & 63, wv = threadIdx.x >> 6;
    const long row = (long)blockIdx.x * 4 + wv;
    const float* p = in + row * 1024 + lane * 16;
    float v[16];
#pragma unroll
    for (int q = 0; q < 4; q++) {
        f32x4 a = *(const f32x4*)(p + q * 4);
#pragma unroll
        for (int e = 0; e < 4; e++) v[q * 4 + e] = a[e];
    }
    float mx = v[0];
#pragma unroll
    for (int i = 1; i < 16; i++) mx = fmaxf(mx, v[i]);
#pragma unroll
    for (int off = 32; off; off >>= 1) mx = fmaxf(mx, __shfl_xor(mx, off, 64));
    float s = 0.f;
#pragma unroll
    for (int i = 0; i < 16; i++) { v[i] = __expf(v[i] - mx); s += v[i]; }
#pragma unroll
    for (int off = 32; off; off >>= 1) s += __shfl_xor(s, off, 64);
    const float inv = 1.0f / s;
    u16* qp = out + row * 1024 + lane * 16;
#pragma unroll
    for (int q = 0; q < 2; q++) {
        u16x8 o;
#pragma unroll
        for (int e = 0; e < 8; e++) o[e] = f2bf(v[q * 8 + e] * inv);
        *(u16x8*)(qp + q * 8) = o;
    }
}

// ---------------------------------------------------------------------------
// out = LayerNorm(a (+bb) + res) * g + beta ; rows of 1024; one wave per row.
// ADDB: add per-column bias bb (fp32) to A before LN (split-K FF2 b2 fold).
// ---------------------------------------------------------------------------
template<int AF32, int RESF32, int OUTF32, int ADDB>
__global__ __launch_bounds__(256)
void ln_res(const void* __restrict__ Av, const void* __restrict__ Rv,
            const float* __restrict__ g, const float* __restrict__ be,
            void* __restrict__ out, const float* __restrict__ bb)
{
    const int lane = threadIdx.x & 63, wv = threadIdx.x >> 6;
    const long row = (long)blockIdx.x * 4 + wv;
    const long off = row * 1024 + lane * 16;
    const int c0 = lane * 16;
    float v[16];
    if (AF32) {
#pragma unroll
        for (int q = 0; q < 4; q++) {
            f32x4 a = *((const f32x4*)((const float*)Av + off) + q);
#pragma unroll
            for (int e = 0; e < 4; e++) v[q * 4 + e] = a[e];
        }
    } else {
#pragma unroll
        for (int q = 0; q < 2; q++) {
            u16x8 a = *((const u16x8*)((const u16*)Av + off) + q);
#pragma unroll
            for (int e = 0; e < 8; e++) v[q * 8 + e] = bf2f(a[e]);
        }
    }
    if (ADDB) {
#pragma unroll
        for (int q = 0; q < 4; q++) {
            f32x4 a = *(const f32x4*)&bb[c0 + q * 4];
#pragma unroll
            for (int e = 0; e < 4; e++) v[q * 4 + e] += a[e];
        }
    }
    if (RESF32) {
#pragma unroll
        for (int q = 0; q < 4; q++) {
            f32x4 a = *((const f32x4*)((const float*)Rv + off) + q);
#pragma unroll
            for (int e = 0; e < 4; e++) v[q * 4 + e] += a[e];
        }
    } else {
#pragma unroll
        for (int q = 0; q < 2; q++) {
            u16x8 a = *((const u16x8*)((const u16*)Rv + off) + q);
#pragma unroll
            for (int e = 0; e < 8; e++) v[q * 8 + e] += bf2f(a[e]);
        }
    }
    float s = 0.f;
#pragma unroll
    for (int i = 0; i < 16; i++) s += v[i];
#pragma unroll
    for (int o = 32; o; o >>= 1) s += __shfl_xor(s, o, 64);
    const float mu = s * (1.f / 1024.f);
    float s2 = 0.f;
#pragma unroll
    for (int i = 0; i < 16; i++) { float d = v[i] - mu; s2 += d * d; }
#pragma unroll
    for (int o = 32; o; o >>= 1) s2 += __shfl_xor(s2, o, 64);
    const float rs = rsqrtf(s2 * (1.f / 1024.f) + 1e-5f);

    float ov[16];
#pragma unroll
    for (int q = 0; q < 4; q++) {
        f32x4 gv = *(const f32x4*)&g[c0 + q * 4];
        f32x4 bv = *(const f32x4*)&be[c0 + q * 4];
#pragma unroll
        for (int e = 0; e < 4; e++)
            ov[q * 4 + e] = (v[q * 4 + e] - mu) * rs * gv[e] + bv[e];
    }
    if (OUTF32) {
#pragma unroll
        for (int q = 0; q < 4; q++) {
            f32x4 o;
#pragma unroll
            for (int e = 0; e < 4; e++) o[e] = ov[q * 4 + e];
            *((f32x4*)((float*)out + off) + q) = o;
        }
    } else {
#pragma unroll
        for (int q = 0; q < 2; q++) {
            u16x8 o;
#pragma unroll
            for (int e = 0; e < 8; e++) o[e] = f2bf(ov[q * 8 + e]);
            *((u16x8*)((u16*)out + off) + q) = o;
        }
    }
}

// ---------------------------------------------------------------------------
// Flash cross-attention. Grid: (8 i-tiles, 16 heads, 4 b). T5 setprio.
// K/V LDS tiles are 64x64 (128B row stride) -> same swizzle as gemm_body:
// slot(c,r) = c ^ (r&7), via permuted global source + XOR'd ds_read.
// ---------------------------------------------------------------------------
__global__ __launch_bounds__(256, 3)
void flash_ca(const u16* __restrict__ P, const u16* __restrict__ Kc,
              const u16* __restrict__ VT, u16* __restrict__ O)
{
    __shared__ alignas(16) u16 Ks[2][64 * 64];
    __shared__ alignas(16) u16 Vs[2][64 * 64];   // [d][j]
    __shared__ alignas(16) u16 Ps[128 * 72];     // per-wave 32-row strips
    const int b = blockIdx.z, h = blockIdx.y, it = blockIdx.x;
    const long base = (long)b * N_ * D_;
    const int t = threadIdx.x, lane = t & 63, w = t >> 6;
    const int fr = lane & 15, fq = lane >> 4;

    bf16x8 qf[2][2];
#pragma unroll
    for (int mt = 0; mt < 2; mt++)
#pragma unroll
        for (int hf = 0; hf < 2; hf++)
            qf[mt][hf] = ld8(&P[base + (long)(it * 128 + w * 32 + mt * 16 + fr) * D_
                                + h * 64 + hf * 32 + fq * 8]);

    // staging: thread t -> row (t>>3), dest slot (t&7); global chunk = slot ^ (row&7)
    const int svr = t >> 3, svc = ((t & 7) ^ (svr & 7)) * 8;
    auto stageK = [&](int buf, int jt) {
#pragma unroll
        for (int p = 0; p < 2; p++)
            gll16(Kc + base + (long)(jt * 64 + p * 32 + svr) * D_ + h * 64 + svc,
                  &Ks[buf][p * 2048 + w * 512]);
    };
    auto stageV = [&](int buf, int jt) {
#pragma unroll
        for (int p = 0; p < 2; p++)
            gll16(VT + base + (long)(h * 64 + p * 32 + svr) * D_ + jt * 64 + svc,
                  &Vs[buf][p * 2048 + w * 512]);
    };

    f32x4 o[2][4] = {};
    float l_lane[2][4] = {};

    stageK(0, 0); stageV(0, 0);
    int cur = 0;
    for (int jt = 0; jt < 16; jt++) {
        __syncthreads();
        if (jt + 1 < 16) { stageK(cur ^ 1, jt + 1); stageV(cur ^ 1, jt + 1); }
        const u16* ks = Ks[cur];
        const u16* vs = Vs[cur];

        f32x4 st[2][4] = {};
        __builtin_amdgcn_s_setprio(1);
#pragma unroll
        for (int nt = 0; nt < 4; nt++) {
            const int row = nt * 16 + fr;
            bf16x8 b0 = ld8(&ks[row * 64 + ((fq ^ (row & 7)) << 3)]);
            bf16x8 b1 = ld8(&ks[row * 64 + (((fq + 4) ^ (row & 7)) << 3)]);
#pragma unroll
            for (int mt = 0; mt < 2; mt++) {
                st[mt][nt] = __builtin_amdgcn_mfma_f32_16x16x32_bf16(qf[mt][0], b0, st[mt][nt], 0, 0, 0);
                st[mt][nt] = __builtin_amdgcn_mfma_f32_16x16x32_bf16(qf[mt][1], b1, st[mt][nt], 0, 0, 0);
            }
        }
        __builtin_amdgcn_s_setprio(0);
#pragma unroll
        for (int mt = 0; mt < 2; mt++)
#pragma unroll
            for (int nt = 0; nt < 4; nt++)
#pragma unroll
                for (int r = 0; r < 4; r++) {
                    float e = __expf(st[mt][nt][r]);
                    l_lane[mt][r] += e;
                    Ps[(w * 32 + mt * 16 + fq * 4 + r) * 72 + nt * 16 + fr] = f2bf(e);
                }
        __asm__ volatile("s_waitcnt lgkmcnt(0)" ::: "memory");
        bf16x8 vf[4][2];
#pragma unroll
        for (int dt = 0; dt < 4; dt++) {
            const int row = dt * 16 + fr;
            vf[dt][0] = ld8(&vs[row * 64 + ((fq ^ (row & 7)) << 3)]);
            vf[dt][1] = ld8(&vs[row * 64 + (((fq + 4) ^ (row & 7)) << 3)]);
        }
        __builtin_amdgcn_s_setprio(1);
#pragma unroll
        for (int mt = 0; mt < 2; mt++) {
            bf16x8 p0 = ld8(&Ps[(w * 32 + mt * 16 + fr) * 72 + fq * 8]);
            bf16x8 p1 = ld8(&Ps[(w * 32 + mt * 16 + fr) * 72 + 32 + fq * 8]);
#pragma unroll
            for (int dt = 0; dt < 4; dt++) {
                o[mt][dt] = __builtin_amdgcn_mfma_f32_16x16x32_bf16(p0, vf[dt][0], o[mt][dt], 0, 0, 0);
                o[mt][dt] = __builtin_amdgcn_mfma_f32_16x16x32_bf16(p1, vf[dt][1], o[mt][dt], 0, 0, 0);
            }
        }
        __builtin_amdgcn_s_setprio(0);
        cur ^= 1;
    }
#pragma unroll
    for (int mt = 0; mt < 2; mt++)
#pragma unroll
        for (int r = 0; r < 4; r++) {
            float lt = l_lane[mt][r];
#pragma unroll
            for (int off = 1; off < 16; off <<= 1) lt += __shfl_xor(lt, off, 64);
            l_lane[mt][r] = 1.0f / lt;
        }
#pragma unroll
    for (int mt = 0; mt < 2; mt++)
#pragma unroll
        for (int dt = 0; dt < 4; dt++)
#pragma unroll
            for (int r = 0; r < 4; r++)
                O[base + (long)(it * 128 + w * 32 + mt * 16 + fq * 4 + r) * D_
                  + h * 64 + dt * 16 + fr] = f2bf(o[mt][dt][r] * l_lane[mt][r]);
}

// ---------------------------------------------------------------------------
extern "C" void kernel_launch(void* const* d_in, const int* in_sizes, int n_in,
                              void* d_out, int out_size, void* d_ws, size_t ws_size,
                              hipStream_t stream)
{
    const float* x     = (const float*)d_in[0];
    const float* enc   = (const float*)d_in[1];
    const float* sa_wq = (const float*)d_in[2];
    const float* sa_wk = (const float*)d_in[3];
    const float* sa_wv = (const float*)d_in[4];
    const float* sa_g  = (const float*)d_in[5];
    const float* sa_b  = (const float*)d_in[6];
    const float* ca_wq = (const float*)d_in[7];
    const float* ca_wk = (const float*)d_in[8];
    const float* ca_wv = (const float*)d_in[9];
    const float* ca_g  = (const float*)d_in[10];
    const float* ca_b  = (const float*)d_in[11];
    const float* w1    = (const float*)d_in[12];
    const float* b1    = (const float*)d_in[13];
    const float* w2    = (const float*)d_in[14];
    const float* b2    = (const float*)d_in[15];
    const float* ff_g  = (const float*)d_in[16];
    const float* ff_b  = (const float*)d_in[17];

    // 76 MB workspace, lifetime-overlaid (MB offsets):
    //  0- 8 xB -> attnB(attn->P) -> w2T
    //  8-16 encB -> w1T
    // 16-22 Wsa ; 22-28 Wca ; 16-32 h2F (after CA, memset-zeroed)
    // 28-36 qB_sa -> E(saln) -> flash O
    // 36-44 kB_sa -> qB(ca) -> calnB
    // 44-52 vTB -> kB(ca) ; 44-76 h1B (FF)
    // 52-60 vcTB
    // 60-76 scF (fp32) ; 60-68 kcT (CA, written by qc|kc epilogue)
    char* ws = (char*)d_ws;
    const size_t MB = 1ull << 20;
    u16*  xB    = (u16*)(ws + 0 * MB);
    u16*  attnB = (u16*)(ws + 0 * MB);
    u16*  w2T   = (u16*)(ws + 0 * MB);
    u16*  encB  = (u16*)(ws + 8 * MB);
    u16*  w1T   = (u16*)(ws + 8 * MB);
    u16*  Wsa   = (u16*)(ws + 16 * MB);   // q@+0, k@+1M, v@+2M elems
    u16*  Wca   = (u16*)(ws + 22 * MB);
    float* h2F  = (float*)(ws + 16 * MB);
    u16*  qBsa  = (u16*)(ws + 28 * MB);
    u16*  E     = (u16*)(ws + 28 * MB);   // saln, then flash O
    u16*  kBsa  = (u16*)(ws + 36 * MB);
    u16*  qBca  = (u16*)(ws + 36 * MB);
    u16*  calnB = (u16*)(ws + 36 * MB);
    u16*  vTB   = (u16*)(ws + 44 * MB);
    u16*  kBca  = (u16*)(ws + 44 * MB);
    u16*  h1B   = (u16*)(ws + 44 * MB);
    u16*  vcTB  = (u16*)(ws + 52 * MB);
    float* scF  = (float*)(ws + 60 * MB);
    u16*  kcT   = (u16*)(ws + 60 * MB);

    const dim3 blk(256, 1, 1);
    const long M1 = (long)N_ * D_;        // 1M elems, per-batch stride
    const long W1M = (long)1024 * 1024;   // weight matrix elems

    // 0) fused prep: x|enc converts + six weight transposes (one dispatch)
    prep_all<<<dim3(10240, 1, 1), blk, 0, stream>>>(
        x, enc, xB, encB, sa_wq, sa_wk, sa_wv, ca_wq, ca_wk, ca_wv, Wsa, Wca);

    // 2) q|k|vT|vcT merged: 1024 blocks of 128x128, 4 blocks/CU.
    gemm_qkv4<<<dim3(1024, 1, 1), blk, 0, stream>>>(
        xB, Wsa, Wsa + W1M, qBsa, kBsa,
        Wsa + 2 * W1M, Wca + 2 * W1M, encB, vTB, vcTB);
    // 4) scores = q k^T / 32 (fp32). grid 8x16x4 = 512, 128x64, BK=64.
    gemm_a<128,64,64,0,1,0,0,0,0><<<dim3(8, 16, 4), blk, 0, stream>>>(
        qBsa, nullptr, kBsa, nullptr, scF, nullptr, nullptr, nullptr,
        0.03125f, 1024, 1024, 1024, 1024, M1, M1, M1);
    softmax_1024<<<dim3(1024, 1, 1), blk, 0, stream>>>(scF, attnB);
    // 5) sa_pre = attn @ v (fp32), BK=64
    gemm_a<128,64,64,0,1,0,0,0,0><<<dim3(8, 16, 4), blk, 0, stream>>>(
        attnB, nullptr, vTB, nullptr, scF, nullptr, nullptr, nullptr,
        1.f, 1024, 1024, 1024, 1024, M1, M1, M1);
    ln_res<1,1,0,0><<<dim3(1024, 1, 1), blk, 0, stream>>>(scF, x, sa_g, sa_b, E, nullptr);

    // 6) qc|kc fused (y-half): qc = saln @ Wq ; kc = encB @ Wk. BK=64.
    //    kc half also scatter-writes kcT (transposed per batch) via WT.
    gemm_a<128,128,64,1,0,0,0,0,1><<<dim3(32, 16, 1), blk, 0, stream>>>(
        E, encB, Wca, Wca + W1M, qBca, kBca, nullptr, kcT,
        1.f, 1024, 1024, 1024, 1024, 0, 0, 0);
    // 8) P = (qc @ kc) / 64, BK=64
    gemm_a<128,64,64,0,0,0,0,0,0><<<dim3(8, 16, 4), blk, 0, stream>>>(
        qBca, nullptr, kcT, nullptr, attnB, nullptr, nullptr, nullptr,
        0.015625f, 1024, 1024, 1024, 1024, M1, M1, M1);
    // 9) flash cross-attn -> O (over saln region)
    flash_ca<<<dim3(8, 16, 4), blk, 0, stream>>>(attnB, kBca, vcTB, E);
    ln_res<0,1,0,0><<<dim3(1024, 1, 1), blk, 0, stream>>>(E, enc, ca_g, ca_b, calnB, nullptr);

    // 10) FeedForward. h2F zero-init for split-K atomic accumulation.
    hipMemsetAsync(h2F, 0, (size_t)16 * MB, stream);
    transpose_ff<<<dim3(128, 32, 2), blk, 0, stream>>>(w1, w2, w1T, w2T);
    gemm_a<128,128,32,0,0,1,1,0,0><<<dim3(32, 32, 1), blk, 0, stream>>>(
        calnB, nullptr, w1T, nullptr, h1B, nullptr, b1, nullptr,
        1.f, 1024, 1024, 1024, 4096, 0, 0, 0);
    // FF2 split-K=4: tile 128x128, BK=32, z = K-chunk; atomicAdd into h2F.
    gemm_a<128,128,32,3,1,0,0,1,0><<<dim3(32, 8, 4), blk, 0, stream>>>(
        h1B, nullptr, w2T, nullptr, h2F, nullptr, nullptr, nullptr,
        1.f, 1024, 4096, 4096, 1024, 0, 0, 0);
    // final LN adds b2 (ADDB) since split-K FF2 skips bias.
    ln_res<1,0,1,1><<<dim3(1024, 1, 1), blk, 0, stream>>>(h2F, calnB, ff_g, ff_b, (float*)d_out, b2);
}

// Round 10
// 466.283 us; speedup vs baseline: 1.0424x; 1.0424x over previous
//
#include <hip/hip_runtime.h>
#include <math.h>
#include <stdint.h>

// B=4, N=1024, D=1024, H=16, DH=64, MLP=4096. Inputs fp32, output fp32.
// Round 19: r9 post-mortem: split-K4+atomicAdd FF2 = 87.9us (WRITE 64MB,
// atomics serialize at L2; MfmaUtil 15.5 despite occ 33.6). Fix: keep the
// 128x128 tile (wave 64x64, 2 MFMA per ds_read_b128 vs 1.33 at 64x32) but
// split-K=2 with DIRECT bf16 stores to two disjoint partials (no atomics,
// no memset; WRITE back to 16MB); p0+p1+b2 folded into final ln_res.
// kcT fusion kept (r9's regression was entirely FF2).
typedef unsigned short u16;
typedef u16   u16x4 __attribute__((ext_vector_type(4)));
typedef u16   u16x8 __attribute__((ext_vector_type(8)));
typedef __bf16 bf16x8 __attribute__((ext_vector_type(8)));
typedef float  f32x4 __attribute__((ext_vector_type(4)));

#define B_   4
#define N_   1024
#define D_   1024
#define MLP_ 4096

__device__ __forceinline__ float bf2f(u16 v) {
    unsigned u = ((unsigned)v) << 16;
    return __builtin_bit_cast(float, u);
}
__device__ __forceinline__ u16 f2bf(float f) {
    unsigned u = __builtin_bit_cast(unsigned, f);
    u += 0x7fff + ((u >> 16) & 1);   // RN-even
    return (u16)(u >> 16);
}
__device__ __forceinline__ bf16x8 ld8(const u16* p) {
    return __builtin_bit_cast(bf16x8, *(const u16x8*)p);
}
// async 16B global -> LDS (lds dest = wave-uniform base + lane*16)
__device__ __forceinline__ void gll16(const u16* g, u16* l) {
    __builtin_amdgcn_global_load_lds(
        (const __attribute__((address_space(1))) unsigned int*)g,
        (__attribute__((address_space(3))) unsigned int*)l,
        16, 0, 0);
}
// GELU(v) = 0.5 v (1 + erf(v/sqrt2)); erf via A&S 7.1.26 (|err|<1.5e-7).
__device__ __forceinline__ float gelu_f(float v) {
    float xs = v * 0.70710678118654752f;     // erf argument
    float ax = fabsf(xs);
    float t  = __builtin_amdgcn_rcpf(fmaf(0.3275911f, ax, 1.0f));
    float p  = fmaf(1.061405429f, t, -1.453152027f);
    p = fmaf(p, t, 1.421413741f);
    p = fmaf(p, t, -0.284496736f);
    p = fmaf(p, t, 0.254829592f);
    p *= t;
    float e = __expf(-ax * ax);
    float er = 1.0f - p * e;                 // erf(|xs|)
    er = copysignf(er, xs);
    return 0.5f * v * (1.0f + er);
}

// ---------------------------------------------------------------------------
// Fused prep: blocks [0,4096) convert x|enc fp32->bf16 (8 elems/thread);
// blocks [4096,10240) do the six 1024x1024 weight transposes (fp32->bf16).
// ---------------------------------------------------------------------------
__global__ __launch_bounds__(256)
void prep_all(const float* __restrict__ x, const float* __restrict__ enc,
              u16* __restrict__ xB, u16* __restrict__ encB,
              const float* __restrict__ p0, const float* __restrict__ p1,
              const float* __restrict__ p2, const float* __restrict__ p3,
              const float* __restrict__ p4, const float* __restrict__ p5,
              u16* __restrict__ Wsa, u16* __restrict__ Wca)
{
    __shared__ u16 tile[32][33];
    int bid = blockIdx.x;
    if (bid < 4096) {
        // ---- convert role ----
        const float* in = x; u16* out = xB;
        if (bid >= 2048) { in = enc; out = encB; bid -= 2048; }
        long i = (long)bid * 256 + threadIdx.x;        // < 524288 exactly
        f32x4 a = *(const f32x4*)&in[i * 8];
        f32x4 b = *(const f32x4*)&in[i * 8 + 4];
        u16x8 h;
        h[0] = f2bf(a[0]); h[1] = f2bf(a[1]); h[2] = f2bf(a[2]); h[3] = f2bf(a[3]);
        h[4] = f2bf(b[0]); h[5] = f2bf(b[1]); h[6] = f2bf(b[2]); h[7] = f2bf(b[3]);
        *(u16x8*)&out[i * 8] = h;
        return;
    }
    // ---- weight-transpose role ----
    int sub = bid - 4096;
    const int z = sub >> 10;          // 0..5
    const int t2 = sub & 1023;
    const int bx = (t2 & 31) * 32, by = (t2 >> 5) * 32;
    const float* in = p0;
    if (z == 1) in = p1;
    else if (z == 2) in = p2;
    else if (z == 3) in = p3;
    else if (z == 4) in = p4;
    else if (z == 5) in = p5;
    u16* out = (z < 3) ? Wsa + (long)z * (1 << 20) : Wca + (long)(z - 3) * (1 << 20);
    const int tx = threadIdx.x & 31, ty = threadIdx.x >> 5;
#pragma unroll
    for (int i = ty; i < 32; i += 8)
        tile[i][tx] = f2bf(in[(long)(by + i) * 1024 + bx + tx]);
    __syncthreads();
#pragma unroll
    for (int i = ty; i < 32; i += 8)
        out[(long)(bx + i) * 1024 + by + tx] = tile[tx][i];
}

// ---------------------------------------------------------------------------
// GEMM body: C[m,n] = scale*sum_k A[m,k]*Bt[n,k] (+bias)(gelu). A,Bt bf16.
// Tile TM x TN x BK, 4 waves (2x2 of TM/2 x TN/2), 16x16x32 bf16 MFMA,
// global_load_lds width=16, double-buffered K-loop (1 barrier per BK).
// T2 swizzle: LDS slot(c, r) = c ^ (r & CMASK) per 16B chunk (rule #21).
// WT: also scatter-write C^T (per-1024-row-batch) to CT as aligned 8B stores.
// ---------------------------------------------------------------------------
template<int TM, int TN, int BK, int OUTF32, int BIAS, int GELU, int WT>
__device__ __forceinline__ void gemm_body(
    const u16* __restrict__ A, const u16* __restrict__ Bt, char* __restrict__ Cp,
    const float* __restrict__ bias, u16* __restrict__ CT, float scale, int K,
    int lda, int ldb, int ldc, int m0, int n0)
{
    constexpr int MT = TM / 32, NT = TN / 32;   // frag tiles per wave
    constexpr int CPT = BK / 8;                 // 16B chunks per LDS row
    constexpr int RPP = 2048 / BK;              // rows staged per 256-thread pass
    constexpr int CMASK = (CPT - 1) & 7;        // swizzle mask (BK=64 -> 7, BK=32 -> 3)
    __shared__ alignas(16) u16 As[2][TM * BK];
    __shared__ alignas(16) u16 Bs[2][TN * BK];
    const int t = threadIdx.x, lane = t & 63, w = t >> 6;
    const int wr = (w >> 1) * (TM / 2), wc = (w & 1) * (TN / 2);
    const int fr = lane & 15, fq = lane >> 4;
    f32x4 acc[MT][NT] = {};

    // staging: 256 threads x 16B = 4KB per pass (RPP rows x BK cols).
    const int r0a = t / CPT;
    const int c0sw = ((t % CPT) ^ (r0a & CMASK)) * 8;
    auto stageA = [&](u16* dst, int k0) {
#pragma unroll
        for (int p = 0; p < TM / RPP; p++)
            gll16(A + (long)(m0 + p * RPP + r0a) * lda + k0 + c0sw, dst + p * 2048 + w * 512);
    };
    auto stageB = [&](u16* dst, int k0) {
#pragma unroll
        for (int p = 0; p < TN / RPP; p++)
            gll16(Bt + (long)(n0 + p * RPP + r0a) * ldb + k0 + c0sw, dst + p * 2048 + w * 512);
    };

    stageA(As[0], 0);
    stageB(Bs[0], 0);
    int cur = 0;
    for (int k0 = 0; k0 < K; k0 += BK) {
        __syncthreads();                       // drains vmcnt -> buf[cur] ready
        if (k0 + BK < K) {
            stageA(As[cur ^ 1], k0 + BK);
            stageB(Bs[cur ^ 1], k0 + BK);
        }
        const u16* as = As[cur];
        const u16* bs = Bs[cur];
#pragma unroll
        for (int kk = 0; kk < BK; kk += 32) {
            bf16x8 af[MT], bfv[NT];
#pragma unroll
            for (int mt = 0; mt < MT; mt++) {
                const int row = wr + mt * 16 + fr;
                af[mt] = ld8(&as[row * BK + ((((kk >> 3) + fq) ^ (row & CMASK)) << 3)]);
            }
#pragma unroll
            for (int nt = 0; nt < NT; nt++) {
                const int row = wc + nt * 16 + fr;
                bfv[nt] = ld8(&bs[row * BK + ((((kk >> 3) + fq) ^ (row & CMASK)) << 3)]);
            }
#pragma unroll
            for (int mt = 0; mt < MT; mt++)
#pragma unroll
                for (int nt = 0; nt < NT; nt++)
                    acc[mt][nt] = __builtin_amdgcn_mfma_f32_16x16x32_bf16(af[mt], bfv[nt], acc[mt][nt], 0, 0, 0);
        }
        cur ^= 1;
    }

    // C/D layout (m89/m91): col = lane&15, row = (lane>>4)*4 + reg.
#pragma unroll
    for (int nt = 0; nt < NT; nt++) {
        const int col = n0 + wc + nt * 16 + fr;
        float bv = 0.f;
        if (BIAS) bv = bias[col];
#pragma unroll
        for (int mt = 0; mt < MT; mt++) {
            const int rbase = m0 + wr + mt * 16 + fq * 4;
            u16 tv[4];
#pragma unroll
            for (int r = 0; r < 4; r++) {
                float v = acc[mt][nt][r] * scale;
                if (BIAS) v += bv;
                if (GELU) v = gelu_f(v);
                long idx = (long)(rbase + r) * ldc + col;
                if (OUTF32) ((float*)Cp)[idx] = v;
                else        ((u16*) Cp)[idx] = f2bf(v);
                if (WT) tv[r] = f2bf(v);
            }
            if (WT && CT) {   // transposed write, folded per-1024-row batch
                long tb = ((long)(rbase >> 10)) * 1048576 + (long)col * 1024 + (rbase & 1023);
                *(u16x4*)&CT[tb] = *(const u16x4*)tv;
            }
        }
    }
}

// ---------------------------------------------------------------------------
// General GEMM dispatch wrapper.
// SEL=0: single problem; bz walks (sA, sB, sC) — used both for batch and
//        for split-K (sA=sB=K-offset, sC=partial stride).
// SEL=1: y-half selects (A0,B0,C0)/(A1,B1,C1); kc-half scatter-writes CT (WT).
// LDS = 4*BK*(TM+TN) bytes. min-waves: 32KB -> 4 blk/CU, 48KB -> 3, 64KB -> 2.
// ---------------------------------------------------------------------------
template<int TM, int TN, int BK, int SEL, int OUTF32, int BIAS, int GELU, int WT>
__global__ __launch_bounds__(256, ((TM + TN >= 256) ? ((BK == 64) ? 2 : 4)
                                                    : ((BK == 64) ? 3 : 4)))
void gemm_a(const u16* __restrict__ A0, const u16* __restrict__ A1,
            const u16* __restrict__ B0, const u16* __restrict__ B1,
            void* __restrict__ C0v, void* __restrict__ C1v,
            const float* __restrict__ bias, u16* __restrict__ CT,
            float scale, int K,
            int lda, int ldb, int ldc,
            long sA, long sB, long sC)
{
    int by = blockIdx.y, bz = blockIdx.z;
    const u16* A = A0; const u16* Bt = B0; char* Cp = (char*)C0v;
    u16* CTp = nullptr;
    if (SEL == 1) {
        int half = gridDim.y >> 1;
        if (by >= half) { A = A1; Bt = B1; Cp = (char*)C1v; by -= half; CTp = CT; }
    }
    A += bz * sA;  Bt += bz * sB;  Cp += bz * sC * (OUTF32 ? 4 : 2);
    gemm_body<TM, TN, BK, OUTF32, BIAS, GELU, WT>(
        A, Bt, Cp, bias, CTp, scale, K, lda, ldb, ldc, blockIdx.x * TM, by * TN);
}

// ---------------------------------------------------------------------------
// Merged q|k|vT|vcT dispatch: 1024 blocks of 128x128, K=1024, BK=32, 4/CU.
//  bid <  512: q|k  (M=4096): bx=bid&31, by=bid>>5; by<8 -> q, else k.
//  bid >= 512: vT|vcT per batch: bx=sub&7, by=(sub>>3)&7, bz=sub>>6;
//              bz<4 -> vT[b]=WsaV x xB[b]^T, else vcT[b]=WcaV x encB[b]^T.
// ---------------------------------------------------------------------------
__global__ __launch_bounds__(256, 4)
void gemm_qkv4(const u16* __restrict__ xB,  const u16* __restrict__ Wq,
               const u16* __restrict__ Wk,  u16* __restrict__ qB,
               u16* __restrict__ kB,
               const u16* __restrict__ Wv,  const u16* __restrict__ Wvc,
               const u16* __restrict__ encB,
               u16* __restrict__ vTB, u16* __restrict__ vcTB)
{
    const long M1 = (long)N_ * D_;
    int bid = blockIdx.x;
    const u16* A; const u16* Bt; u16* C; int m0, n0;
    if (bid < 512) {
        int bx = bid & 31, by = bid >> 5;
        A = xB; m0 = bx * 128;
        if (by < 8) { Bt = Wq; C = qB; n0 = by * 128; }
        else        { Bt = Wk; C = kB; n0 = (by - 8) * 128; }
    } else {
        int sub = bid - 512;
        int bx = sub & 7, by = (sub >> 3) & 7, bz = sub >> 6;
        m0 = bx * 128; n0 = by * 128;
        if (bz < 4) { A = Wv;  Bt = xB   + (long)bz * M1;       C = vTB  + (long)bz * M1; }
        else        { A = Wvc; Bt = encB + (long)(bz - 4) * M1; C = vcTB + (long)(bz - 4) * M1; }
    }
    gemm_body<128, 128, 32, 0, 0, 0, 0>(
        A, Bt, (char*)C, nullptr, nullptr, 1.f, 1024, 1024, 1024, 1024, m0, n0);
}

// ---------------------------------------------------------------------------
// w1 [1024,4096] and w2 [4096,1024] transposes fused: grid (128, 32, 2).
// z=0: direct tiles for w1. z=1: remap (bx,by) -> (bx>>2, by*4 + (bx&3)).
// ---------------------------------------------------------------------------
__global__ __launch_bounds__(256)
void transpose_ff(const float* __restrict__ w1, const float* __restrict__ w2,
                  u16* __restrict__ o1, u16* __restrict__ o2)
{
    __shared__ u16 tile[32][33];
    const float* in; u16* out; int R, C, bx, by;
    if (blockIdx.z == 0) {
        in = w1; out = o1; R = 1024; C = 4096;
        bx = blockIdx.x; by = blockIdx.y;                 // bx<128, by<32
    } else {
        in = w2; out = o2; R = 4096; C = 1024;
        bx = blockIdx.x >> 2; by = blockIdx.y * 4 + (blockIdx.x & 3);  // bx<32, by<128
    }
    const int x0 = bx * 32, y0 = by * 32;
    const int tx = threadIdx.x & 31, ty = threadIdx.x >> 5;
#pragma unroll
    for (int i = ty; i < 32; i += 8)
        tile[i][tx] = f2bf(in[(long)(y0 + i) * C + x0 + tx]);
    __syncthreads();
#pragma unroll
    for (int i = ty; i < 32; i += 8)
        out[(long)(x0 + i) * R + y0 + tx] = tile[tx][i];
}

// ---------------------------------------------------------------------------
// Row softmax: 1024 fp32 in -> 1024 bf16 out; one wave per row.
// Lane owns 16 contiguous cols (f32x4 loads / u16x8 stores).
// ---------------------------------------------------------------------------
__global__ __launch_bounds__(256)
void softmax_1024(const float* __restrict__ in, u16* __restrict__ out)
{
    const int lane = threadIdx.x & 63, wv = threadIdx.x >> 6;
    const long row = (long)blockIdx.x * 4 + wv;
    const float* p = in + row * 1024 + lane * 16;
    float v[16];
#pragma unroll
    for (int q = 0; q < 4; q++) {
        f32x4 a = *(const f32x4*)(p + q * 4);
#pragma unroll
        for (int e = 0; e < 4; e++) v[q * 4 + e] = a[e];
    }
    float mx = v[0];
#pragma unroll
    for (int i = 1; i < 16; i++) mx = fmaxf(mx, v[i]);
#pragma unroll
    for (int off = 32; off; off >>= 1) mx = fmaxf(mx, __shfl_xor(mx, off, 64));
    float s = 0.f;
#pragma unroll
    for (int i = 0; i < 16; i++) { v[i] = __expf(v[i] - mx); s += v[i]; }
#pragma unroll
    for (int off = 32; off; off >>= 1) s += __shfl_xor(s, off, 64);
    const float inv = 1.0f / s;
    u16* qp = out + row * 1024 + lane * 16;
#pragma unroll
    for (int q = 0; q < 2; q++) {
        u16x8 o;
#pragma unroll
        for (int e = 0; e < 8; e++) o[e] = f2bf(v[q * 8 + e] * inv);
        *(u16x8*)(qp + q * 8) = o;
    }
}

// ---------------------------------------------------------------------------
// out = LayerNorm(a (+a2) (+bb) + res) * g + beta ; rows of 1024; 1 wave/row.
// ADDB: add per-column fp32 bias bb. A2: add second bf16 array Av2
// (split-K partial fold).
// ---------------------------------------------------------------------------
template<int AF32, int RESF32, int OUTF32, int ADDB, int A2>
__global__ __launch_bounds__(256)
void ln_res(const void* __restrict__ Av, const void* __restrict__ Rv,
            const float* __restrict__ g, const float* __restrict__ be,
            void* __restrict__ out, const float* __restrict__ bb,
            const u16* __restrict__ Av2)
{
    const int lane = threadIdx.x & 63, wv = threadIdx.x >> 6;
    const long row = (long)blockIdx.x * 4 + wv;
    const long off = row * 1024 + lane * 16;
    const int c0 = lane * 16;
    float v[16];
    if (AF32) {
#pragma unroll
        for (int q = 0; q < 4; q++) {
            f32x4 a = *((const f32x4*)((const float*)Av + off) + q);
#pragma unroll
            for (int e = 0; e < 4; e++) v[q * 4 + e] = a[e];
        }
    } else {
#pragma unroll
        for (int q = 0; q < 2; q++) {
            u16x8 a = *((const u16x8*)((const u16*)Av + off) + q);
#pragma unroll
            for (int e = 0; e < 8; e++) v[q * 8 + e] = bf2f(a[e]);
        }
    }
    if (A2) {
#pragma unroll
        for (int q = 0; q < 2; q++) {
            u16x8 a = *((const u16x8*)(Av2 + off) + q);
#pragma unroll
            for (int e = 0; e < 8; e++) v[q * 8 + e] += bf2f(a[e]);
        }
    }
    if (ADDB) {
#pragma unroll
        for (int q = 0; q < 4; q++) {
            f32x4 a = *(const f32x4*)&bb[c0 + q * 4];
#pragma unroll
            for (int e = 0; e < 4; e++) v[q * 4 + e] += a[e];
        }
    }
    if (RESF32) {
#pragma unroll
        for (int q = 0; q < 4; q++) {
            f32x4 a = *((const f32x4*)((const float*)Rv + off) + q);
#pragma unroll
            for (int e = 0; e < 4; e++) v[q * 4 + e] += a[e];
        }
    } else {
#pragma unroll
        for (int q = 0; q < 2; q++) {
            u16x8 a = *((const u16x8*)((const u16*)Rv + off) + q);
#pragma unroll
            for (int e = 0; e < 8; e++) v[q * 8 + e] += bf2f(a[e]);
        }
    }
    float s = 0.f;
#pragma unroll
    for (int i = 0; i < 16; i++) s += v[i];
#pragma unroll
    for (int o = 32; o; o >>= 1) s += __shfl_xor(s, o, 64);
    const float mu = s * (1.f / 1024.f);
    float s2 = 0.f;
#pragma unroll
    for (int i = 0; i < 16; i++) { float d = v[i] - mu; s2 += d * d; }
#pragma unroll
    for (int o = 32; o; o >>= 1) s2 += __shfl_xor(s2, o, 64);
    const float rs = rsqrtf(s2 * (1.f / 1024.f) + 1e-5f);

    float ov[16];
#pragma unroll
    for (int q = 0; q < 4; q++) {
        f32x4 gv = *(const f32x4*)&g[c0 + q * 4];
        f32x4 bv = *(const f32x4*)&be[c0 + q * 4];
#pragma unroll
        for (int e = 0; e < 4; e++)
            ov[q * 4 + e] = (v[q * 4 + e] - mu) * rs * gv[e] + bv[e];
    }
    if (OUTF32) {
#pragma unroll
        for (int q = 0; q < 4; q++) {
            f32x4 o;
#pragma unroll
            for (int e = 0; e < 4; e++) o[e] = ov[q * 4 + e];
            *((f32x4*)((float*)out + off) + q) = o;
        }
    } else {
#pragma unroll
        for (int q = 0; q < 2; q++) {
            u16x8 o;
#pragma unroll
            for (int e = 0; e < 8; e++) o[e] = f2bf(ov[q * 8 + e]);
            *((u16x8*)((u16*)out + off) + q) = o;
        }
    }
}

// ---------------------------------------------------------------------------
// Flash cross-attention. Grid: (8 i-tiles, 16 heads, 4 b). T5 setprio.
// K/V LDS tiles are 64x64 (128B row stride) -> same swizzle as gemm_body:
// slot(c,r) = c ^ (r&7), via permuted global source + XOR'd ds_read.
// ---------------------------------------------------------------------------
__global__ __launch_bounds__(256, 3)
void flash_ca(const u16* __restrict__ P, const u16* __restrict__ Kc,
              const u16* __restrict__ VT, u16* __restrict__ O)
{
    __shared__ alignas(16) u16 Ks[2][64 * 64];
    __shared__ alignas(16) u16 Vs[2][64 * 64];   // [d][j]
    __shared__ alignas(16) u16 Ps[128 * 72];     // per-wave 32-row strips
    const int b = blockIdx.z, h = blockIdx.y, it = blockIdx.x;
    const long base = (long)b * N_ * D_;
    const int t = threadIdx.x, lane = t & 63, w = t >> 6;
    const int fr = lane & 15, fq = lane >> 4;

    bf16x8 qf[2][2];
#pragma unroll
    for (int mt = 0; mt < 2; mt++)
#pragma unroll
        for (int hf = 0; hf < 2; hf++)
            qf[mt][hf] = ld8(&P[base + (long)(it * 128 + w * 32 + mt * 16 + fr) * D_
                                + h * 64 + hf * 32 + fq * 8]);

    // staging: thread t -> row (t>>3), dest slot (t&7); global chunk = slot ^ (row&7)
    const int svr = t >> 3, svc = ((t & 7) ^ (svr & 7)) * 8;
    auto stageK = [&](int buf, int jt) {
#pragma unroll
        for (int p = 0; p < 2; p++)
            gll16(Kc + base + (long)(jt * 64 + p * 32 + svr) * D_ + h * 64 + svc,
                  &Ks[buf][p * 2048 + w * 512]);
    };
    auto stageV = [&](int buf, int jt) {
#pragma unroll
        for (int p = 0; p < 2; p++)
            gll16(VT + base + (long)(h * 64 + p * 32 + svr) * D_ + jt * 64 + svc,
                  &Vs[buf][p * 2048 + w * 512]);
    };

    f32x4 o[2][4] = {};
    float l_lane[2][4] = {};

    stageK(0, 0); stageV(0, 0);
    int cur = 0;
    for (int jt = 0; jt < 16; jt++) {
        __syncthreads();
        if (jt + 1 < 16) { stageK(cur ^ 1, jt + 1); stageV(cur ^ 1, jt + 1); }
        const u16* ks = Ks[cur];
        const u16* vs = Vs[cur];

        f32x4 st[2][4] = {};
        __builtin_amdgcn_s_setprio(1);
#pragma unroll
        for (int nt = 0; nt < 4; nt++) {
            const int row = nt * 16 + fr;
            bf16x8 b0 = ld8(&ks[row * 64 + ((fq ^ (row & 7)) << 3)]);
            bf16x8 b1 = ld8(&ks[row * 64 + (((fq + 4) ^ (row & 7)) << 3)]);
#pragma unroll
            for (int mt = 0; mt < 2; mt++) {
                st[mt][nt] = __builtin_amdgcn_mfma_f32_16x16x32_bf16(qf[mt][0], b0, st[mt][nt], 0, 0, 0);
                st[mt][nt] = __builtin_amdgcn_mfma_f32_16x16x32_bf16(qf[mt][1], b1, st[mt][nt], 0, 0, 0);
            }
        }
        __builtin_amdgcn_s_setprio(0);
#pragma unroll
        for (int mt = 0; mt < 2; mt++)
#pragma unroll
            for (int nt = 0; nt < 4; nt++)
#pragma unroll
                for (int r = 0; r < 4; r++) {
                    float e = __expf(st[mt][nt][r]);
                    l_lane[mt][r] += e;
                    Ps[(w * 32 + mt * 16 + fq * 4 + r) * 72 + nt * 16 + fr] = f2bf(e);
                }
        __asm__ volatile("s_waitcnt lgkmcnt(0)" ::: "memory");
        bf16x8 vf[4][2];
#pragma unroll
        for (int dt = 0; dt < 4; dt++) {
            const int row = dt * 16 + fr;
            vf[dt][0] = ld8(&vs[row * 64 + ((fq ^ (row & 7)) << 3)]);
            vf[dt][1] = ld8(&vs[row * 64 + (((fq + 4) ^ (row & 7)) << 3)]);
        }
        __builtin_amdgcn_s_setprio(1);
#pragma unroll
        for (int mt = 0; mt < 2; mt++) {
            bf16x8 p0 = ld8(&Ps[(w * 32 + mt * 16 + fr) * 72 + fq * 8]);
            bf16x8 p1 = ld8(&Ps[(w * 32 + mt * 16 + fr) * 72 + 32 + fq * 8]);
#pragma unroll
            for (int dt = 0; dt < 4; dt++) {
                o[mt][dt] = __builtin_amdgcn_mfma_f32_16x16x32_bf16(p0, vf[dt][0], o[mt][dt], 0, 0, 0);
                o[mt][dt] = __builtin_amdgcn_mfma_f32_16x16x32_bf16(p1, vf[dt][1], o[mt][dt], 0, 0, 0);
            }
        }
        __builtin_amdgcn_s_setprio(0);
        cur ^= 1;
    }
#pragma unroll
    for (int mt = 0; mt < 2; mt++)
#pragma unroll
        for (int r = 0; r < 4; r++) {
            float lt = l_lane[mt][r];
#pragma unroll
            for (int off = 1; off < 16; off <<= 1) lt += __shfl_xor(lt, off, 64);
            l_lane[mt][r] = 1.0f / lt;
        }
#pragma unroll
    for (int mt = 0; mt < 2; mt++)
#pragma unroll
        for (int dt = 0; dt < 4; dt++)
#pragma unroll
            for (int r = 0; r < 4; r++)
                O[base + (long)(it * 128 + w * 32 + mt * 16 + fq * 4 + r) * D_
                  + h * 64 + dt * 16 + fr] = f2bf(o[mt][dt][r] * l_lane[mt][r]);
}

// ---------------------------------------------------------------------------
extern "C" void kernel_launch(void* const* d_in, const int* in_sizes, int n_in,
                              void* d_out, int out_size, void* d_ws, size_t ws_size,
                              hipStream_t stream)
{
    const float* x     = (const float*)d_in[0];
    const float* enc   = (const float*)d_in[1];
    const float* sa_wq = (const float*)d_in[2];
    const float* sa_wk = (const float*)d_in[3];
    const float* sa_wv = (const float*)d_in[4];
    const float* sa_g  = (const float*)d_in[5];
    const float* sa_b  = (const float*)d_in[6];
    const float* ca_wq = (const float*)d_in[7];
    const float* ca_wk = (const float*)d_in[8];
    const float* ca_wv = (const float*)d_in[9];
    const float* ca_g  = (const float*)d_in[10];
    const float* ca_b  = (const float*)d_in[11];
    const float* w1    = (const float*)d_in[12];
    const float* b1    = (const float*)d_in[13];
    const float* w2    = (const float*)d_in[14];
    const float* b2    = (const float*)d_in[15];
    const float* ff_g  = (const float*)d_in[16];
    const float* ff_b  = (const float*)d_in[17];

    // 76 MB workspace, lifetime-overlaid (MB offsets):
    //  0- 8 xB -> attnB(attn->P) -> w2T
    //  8-16 encB -> w1T
    // 16-22 Wsa ; 22-28 Wca ; 16-32 h2P[2] (bf16 split-K partials, FF phase)
    // 28-36 qB_sa -> E(saln) -> flash O
    // 36-44 kB_sa -> qB(ca) -> calnB
    // 44-52 vTB -> kB(ca) ; 44-76 h1B (FF)
    // 52-60 vcTB
    // 60-76 scF (fp32) ; 60-68 kcT (CA, written by qc|kc epilogue)
    char* ws = (char*)d_ws;
    const size_t MB = 1ull << 20;
    u16*  xB    = (u16*)(ws + 0 * MB);
    u16*  attnB = (u16*)(ws + 0 * MB);
    u16*  w2T   = (u16*)(ws + 0 * MB);
    u16*  encB  = (u16*)(ws + 8 * MB);
    u16*  w1T   = (u16*)(ws + 8 * MB);
    u16*  Wsa   = (u16*)(ws + 16 * MB);   // q@+0, k@+1M, v@+2M elems
    u16*  Wca   = (u16*)(ws + 22 * MB);
    u16*  h2P   = (u16*)(ws + 16 * MB);   // split-K partials: p0, p1 (8MB each)
    u16*  qBsa  = (u16*)(ws + 28 * MB);
    u16*  E     = (u16*)(ws + 28 * MB);   // saln, then flash O
    u16*  kBsa  = (u16*)(ws + 36 * MB);
    u16*  qBca  = (u16*)(ws + 36 * MB);
    u16*  calnB = (u16*)(ws + 36 * MB);
    u16*  vTB   = (u16*)(ws + 44 * MB);
    u16*  kBca  = (u16*)(ws + 44 * MB);
    u16*  h1B   = (u16*)(ws + 44 * MB);
    u16*  vcTB  = (u16*)(ws + 52 * MB);
    float* scF  = (float*)(ws + 60 * MB);
    u16*  kcT   = (u16*)(ws + 60 * MB);

    const dim3 blk(256, 1, 1);
    const long M1 = (long)N_ * D_;        // 1M elems, per-batch stride
    const long W1M = (long)1024 * 1024;   // weight matrix elems

    // 0) fused prep: x|enc converts + six weight transposes (one dispatch)
    prep_all<<<dim3(10240, 1, 1), blk, 0, stream>>>(
        x, enc, xB, encB, sa_wq, sa_wk, sa_wv, ca_wq, ca_wk, ca_wv, Wsa, Wca);

    // 2) q|k|vT|vcT merged: 1024 blocks of 128x128, 4 blocks/CU.
    gemm_qkv4<<<dim3(1024, 1, 1), blk, 0, stream>>>(
        xB, Wsa, Wsa + W1M, qBsa, kBsa,
        Wsa + 2 * W1M, Wca + 2 * W1M, encB, vTB, vcTB);
    // 4) scores = q k^T / 32 (fp32). grid 8x16x4 = 512, 128x64, BK=64.
    gemm_a<128,64,64,0,1,0,0,0><<<dim3(8, 16, 4), blk, 0, stream>>>(
        qBsa, nullptr, kBsa, nullptr, scF, nullptr, nullptr, nullptr,
        0.03125f, 1024, 1024, 1024, 1024, M1, M1, M1);
    softmax_1024<<<dim3(1024, 1, 1), blk, 0, stream>>>(scF, attnB);
    // 5) sa_pre = attn @ v (fp32), BK=64
    gemm_a<128,64,64,0,1,0,0,0><<<dim3(8, 16, 4), blk, 0, stream>>>(
        attnB, nullptr, vTB, nullptr, scF, nullptr, nullptr, nullptr,
        1.f, 1024, 1024, 1024, 1024, M1, M1, M1);
    ln_res<1,1,0,0,0><<<dim3(1024, 1, 1), blk, 0, stream>>>(
        scF, x, sa_g, sa_b, E, nullptr, nullptr);

    // 6) qc|kc fused (y-half): qc = saln @ Wq ; kc = encB @ Wk. BK=64.
    //    kc half also scatter-writes kcT (transposed per batch) via WT.
    gemm_a<128,128,64,1,0,0,0,1><<<dim3(32, 16, 1), blk, 0, stream>>>(
        E, encB, Wca, Wca + W1M, qBca, kBca, nullptr, kcT,
        1.f, 1024, 1024, 1024, 1024, 0, 0, 0);
    // 8) P = (qc @ kc) / 64, BK=64
    gemm_a<128,64,64,0,0,0,0,0><<<dim3(8, 16, 4), blk, 0, stream>>>(
        qBca, nullptr, kcT, nullptr, attnB, nullptr, nullptr, nullptr,
        0.015625f, 1024, 1024, 1024, 1024, M1, M1, M1);
    // 9) flash cross-attn -> O (over saln region)
    flash_ca<<<dim3(8, 16, 4), blk, 0, stream>>>(attnB, kBca, vcTB, E);
    ln_res<0,1,0,0,0><<<dim3(1024, 1, 1), blk, 0, stream>>>(
        E, enc, ca_g, ca_b, calnB, nullptr, nullptr);

    // 10) FeedForward.
    transpose_ff<<<dim3(128, 32, 2), blk, 0, stream>>>(w1, w2, w1T, w2T);
    gemm_a<128,128,32,0,0,1,1,0><<<dim3(32, 32, 1), blk, 0, stream>>>(
        calnB, nullptr, w1T, nullptr, h1B, nullptr, b1, nullptr,
        1.f, 1024, 1024, 1024, 4096, 0, 0, 0);
    // FF2 split-K=2, DIRECT bf16 stores: z in {0,1}; A,Bt advance 2048 along
    // K (sA=sB=2048, lda=ldb=4096); partial z at h2P + z*4M elems (sC=4M).
    gemm_a<128,128,32,0,0,0,0,0><<<dim3(32, 8, 2), blk, 0, stream>>>(
        h1B, nullptr, w2T, nullptr, h2P, nullptr, nullptr, nullptr,
        1.f, 2048, 4096, 4096, 1024, 2048, 2048, 4194304);
    // final LN folds p0 + p1 (A2) + b2 (ADDB) + residual calnB.
    ln_res<0,0,1,1,1><<<dim3(1024, 1, 1), blk, 0, stream>>>(
        h2P, calnB, ff_g, ff_b, (float*)d_out, b2, h2P + 4194304);
}

// Round 11
// 458.338 us; speedup vs baseline: 1.0605x; 1.0173x over previous
//
#include <hip/hip_runtime.h>
#include <math.h>
#include <stdint.h>

// B=4, N=1024, D=1024, H=16, DH=64, MLP=4096. Inputs fp32, output fp32.
// Round 20: r10 post-mortem: (a) kcT scatter fusion was net +9us
// (2KB-strided 8B stores) -> REVERTED to transpose_cast; (b) FF2 split-K2
// kept (-3.3 measured); (c) wave-tile-ratio lever refuted (MfmaUtil pinned
// ~22% at 2-blk/CU 2-phase) -> FF1 gets the structural fix: 256^2 tile,
// 8 waves (2x4), BK=64, 128KB dbuf LDS, 1 blk/CU, 4-phase interleave
// {stage-early || quadrant ds_read || 16-MFMA setprio cluster}, ONE
// __syncthreads per K-step (drain is free: loads issued >=2 phases early).
typedef unsigned short u16;
typedef u16   u16x4 __attribute__((ext_vector_type(4)));
typedef u16   u16x8 __attribute__((ext_vector_type(8)));
typedef __bf16 bf16x8 __attribute__((ext_vector_type(8)));
typedef float  f32x4 __attribute__((ext_vector_type(4)));

#define B_   4
#define N_   1024
#define D_   1024
#define MLP_ 4096

__device__ __forceinline__ float bf2f(u16 v) {
    unsigned u = ((unsigned)v) << 16;
    return __builtin_bit_cast(float, u);
}
__device__ __forceinline__ u16 f2bf(float f) {
    unsigned u = __builtin_bit_cast(unsigned, f);
    u += 0x7fff + ((u >> 16) & 1);   // RN-even
    return (u16)(u >> 16);
}
__device__ __forceinline__ bf16x8 ld8(const u16* p) {
    return __builtin_bit_cast(bf16x8, *(const u16x8*)p);
}
// async 16B global -> LDS (lds dest = wave-uniform base + lane*16)
__device__ __forceinline__ void gll16(const u16* g, u16* l) {
    __builtin_amdgcn_global_load_lds(
        (const __attribute__((address_space(1))) unsigned int*)g,
        (__attribute__((address_space(3))) unsigned int*)l,
        16, 0, 0);
}
// GELU(v) = 0.5 v (1 + erf(v/sqrt2)); erf via A&S 7.1.26 (|err|<1.5e-7).
__device__ __forceinline__ float gelu_f(float v) {
    float xs = v * 0.70710678118654752f;     // erf argument
    float ax = fabsf(xs);
    float t  = __builtin_amdgcn_rcpf(fmaf(0.3275911f, ax, 1.0f));
    float p  = fmaf(1.061405429f, t, -1.453152027f);
    p = fmaf(p, t, 1.421413741f);
    p = fmaf(p, t, -0.284496736f);
    p = fmaf(p, t, 0.254829592f);
    p *= t;
    float e = __expf(-ax * ax);
    float er = 1.0f - p * e;                 // erf(|xs|)
    er = copysignf(er, xs);
    return 0.5f * v * (1.0f + er);
}

// ---------------------------------------------------------------------------
// Fused prep: blocks [0,4096) convert x|enc fp32->bf16 (8 elems/thread);
// blocks [4096,10240) do the six 1024x1024 weight transposes (fp32->bf16).
// ---------------------------------------------------------------------------
__global__ __launch_bounds__(256)
void prep_all(const float* __restrict__ x, const float* __restrict__ enc,
              u16* __restrict__ xB, u16* __restrict__ encB,
              const float* __restrict__ p0, const float* __restrict__ p1,
              const float* __restrict__ p2, const float* __restrict__ p3,
              const float* __restrict__ p4, const float* __restrict__ p5,
              u16* __restrict__ Wsa, u16* __restrict__ Wca)
{
    __shared__ u16 tile[32][33];
    int bid = blockIdx.x;
    if (bid < 4096) {
        // ---- convert role ----
        const float* in = x; u16* out = xB;
        if (bid >= 2048) { in = enc; out = encB; bid -= 2048; }
        long i = (long)bid * 256 + threadIdx.x;        // < 524288 exactly
        f32x4 a = *(const f32x4*)&in[i * 8];
        f32x4 b = *(const f32x4*)&in[i * 8 + 4];
        u16x8 h;
        h[0] = f2bf(a[0]); h[1] = f2bf(a[1]); h[2] = f2bf(a[2]); h[3] = f2bf(a[3]);
        h[4] = f2bf(b[0]); h[5] = f2bf(b[1]); h[6] = f2bf(b[2]); h[7] = f2bf(b[3]);
        *(u16x8*)&out[i * 8] = h;
        return;
    }
    // ---- weight-transpose role ----
    int sub = bid - 4096;
    const int z = sub >> 10;          // 0..5
    const int t2 = sub & 1023;
    const int bx = (t2 & 31) * 32, by = (t2 >> 5) * 32;
    const float* in = p0;
    if (z == 1) in = p1;
    else if (z == 2) in = p2;
    else if (z == 3) in = p3;
    else if (z == 4) in = p4;
    else if (z == 5) in = p5;
    u16* out = (z < 3) ? Wsa + (long)z * (1 << 20) : Wca + (long)(z - 3) * (1 << 20);
    const int tx = threadIdx.x & 31, ty = threadIdx.x >> 5;
#pragma unroll
    for (int i = ty; i < 32; i += 8)
        tile[i][tx] = f2bf(in[(long)(by + i) * 1024 + bx + tx]);
    __syncthreads();
#pragma unroll
    for (int i = ty; i < 32; i += 8)
        out[(long)(bx + i) * 1024 + by + tx] = tile[tx][i];
}

// ---------------------------------------------------------------------------
// GEMM body: C[m,n] = scale*sum_k A[m,k]*Bt[n,k] (+bias)(gelu). A,Bt bf16.
// Tile TM x TN x BK, 4 waves (2x2 of TM/2 x TN/2), 16x16x32 bf16 MFMA,
// global_load_lds width=16, double-buffered K-loop (1 barrier per BK).
// T2 swizzle: LDS slot(c, r) = c ^ (r & CMASK) per 16B chunk (rule #21).
// ---------------------------------------------------------------------------
template<int TM, int TN, int BK, int OUTF32, int BIAS, int GELU>
__device__ __forceinline__ void gemm_body(
    const u16* __restrict__ A, const u16* __restrict__ Bt, char* __restrict__ Cp,
    const float* __restrict__ bias, float scale, int K,
    int lda, int ldb, int ldc, int m0, int n0)
{
    constexpr int MT = TM / 32, NT = TN / 32;   // frag tiles per wave
    constexpr int CPT = BK / 8;                 // 16B chunks per LDS row
    constexpr int RPP = 2048 / BK;              // rows staged per 256-thread pass
    constexpr int CMASK = (CPT - 1) & 7;        // swizzle mask (BK=64 -> 7, BK=32 -> 3)
    __shared__ alignas(16) u16 As[2][TM * BK];
    __shared__ alignas(16) u16 Bs[2][TN * BK];
    const int t = threadIdx.x, lane = t & 63, w = t >> 6;
    const int wr = (w >> 1) * (TM / 2), wc = (w & 1) * (TN / 2);
    const int fr = lane & 15, fq = lane >> 4;
    f32x4 acc[MT][NT] = {};

    // staging: 256 threads x 16B = 4KB per pass (RPP rows x BK cols).
    const int r0a = t / CPT;
    const int c0sw = ((t % CPT) ^ (r0a & CMASK)) * 8;
    auto stageA = [&](u16* dst, int k0) {
#pragma unroll
        for (int p = 0; p < TM / RPP; p++)
            gll16(A + (long)(m0 + p * RPP + r0a) * lda + k0 + c0sw, dst + p * 2048 + w * 512);
    };
    auto stageB = [&](u16* dst, int k0) {
#pragma unroll
        for (int p = 0; p < TN / RPP; p++)
            gll16(Bt + (long)(n0 + p * RPP + r0a) * ldb + k0 + c0sw, dst + p * 2048 + w * 512);
    };

    stageA(As[0], 0);
    stageB(Bs[0], 0);
    int cur = 0;
    for (int k0 = 0; k0 < K; k0 += BK) {
        __syncthreads();                       // drains vmcnt -> buf[cur] ready
        if (k0 + BK < K) {
            stageA(As[cur ^ 1], k0 + BK);
            stageB(Bs[cur ^ 1], k0 + BK);
        }
        const u16* as = As[cur];
        const u16* bs = Bs[cur];
#pragma unroll
        for (int kk = 0; kk < BK; kk += 32) {
            bf16x8 af[MT], bfv[NT];
#pragma unroll
            for (int mt = 0; mt < MT; mt++) {
                const int row = wr + mt * 16 + fr;
                af[mt] = ld8(&as[row * BK + ((((kk >> 3) + fq) ^ (row & CMASK)) << 3)]);
            }
#pragma unroll
            for (int nt = 0; nt < NT; nt++) {
                const int row = wc + nt * 16 + fr;
                bfv[nt] = ld8(&bs[row * BK + ((((kk >> 3) + fq) ^ (row & CMASK)) << 3)]);
            }
#pragma unroll
            for (int mt = 0; mt < MT; mt++)
#pragma unroll
                for (int nt = 0; nt < NT; nt++)
                    acc[mt][nt] = __builtin_amdgcn_mfma_f32_16x16x32_bf16(af[mt], bfv[nt], acc[mt][nt], 0, 0, 0);
        }
        cur ^= 1;
    }

    // C/D layout (m89/m91): col = lane&15, row = (lane>>4)*4 + reg.
#pragma unroll
    for (int nt = 0; nt < NT; nt++) {
        const int col = n0 + wc + nt * 16 + fr;
        float bv = 0.f;
        if (BIAS) bv = bias[col];
#pragma unroll
        for (int mt = 0; mt < MT; mt++) {
            const int rbase = m0 + wr + mt * 16 + fq * 4;
#pragma unroll
            for (int r = 0; r < 4; r++) {
                float v = acc[mt][nt][r] * scale;
                if (BIAS) v += bv;
                if (GELU) v = gelu_f(v);
                long idx = (long)(rbase + r) * ldc + col;
                if (OUTF32) ((float*)Cp)[idx] = v;
                else        ((u16*) Cp)[idx] = f2bf(v);
            }
        }
    }
}

// ---------------------------------------------------------------------------
// General GEMM dispatch wrapper.
// SEL=0: single problem; bz walks (sA, sB, sC) — batch or split-K.
// SEL=1: y-half selects (A0,B0,C0)/(A1,B1,C1).
// LDS = 4*BK*(TM+TN) bytes. min-waves: 32KB -> 4 blk/CU, 48KB -> 3, 64KB -> 2.
// ---------------------------------------------------------------------------
template<int TM, int TN, int BK, int SEL, int OUTF32, int BIAS, int GELU>
__global__ __launch_bounds__(256, ((TM + TN >= 256) ? ((BK == 64) ? 2 : 4)
                                                    : ((BK == 64) ? 3 : 4)))
void gemm_a(const u16* __restrict__ A0, const u16* __restrict__ A1,
            const u16* __restrict__ B0, const u16* __restrict__ B1,
            void* __restrict__ C0v, void* __restrict__ C1v,
            const float* __restrict__ bias,
            float scale, int K,
            int lda, int ldb, int ldc,
            long sA, long sB, long sC)
{
    int by = blockIdx.y, bz = blockIdx.z;
    const u16* A = A0; const u16* Bt = B0; char* Cp = (char*)C0v;
    if (SEL == 1) {
        int half = gridDim.y >> 1;
        if (by >= half) { A = A1; Bt = B1; Cp = (char*)C1v; by -= half; }
    }
    A += bz * sA;  Bt += bz * sB;  Cp += bz * sC * (OUTF32 ? 4 : 2);
    gemm_body<TM, TN, BK, OUTF32, BIAS, GELU>(
        A, Bt, Cp, bias, scale, K, lda, ldb, ldc, blockIdx.x * TM, by * TN);
}

// ---------------------------------------------------------------------------
// FF1 structural kernel: C[4096,4096] = gelu(A[4096,1024] @ Bt[4096,1024]^T
// + bias), bf16 out. 256x256 tile, 8 waves (2x4, wave tile 128x64), BK=64,
// LDS 128KB dbuf -> 1 block/CU. Grid (16,16) = 256 blocks.
// Per K-step: 4 phases {stage-early, quadrant ds_read, 16-MFMA setprio
// cluster}; ONE __syncthreads at K-step end (vmcnt drain hidden: all 8
// staging issues occur in phases 0-1). Swizzle: slot(c,r)=c^(r&7).
// ---------------------------------------------------------------------------
__global__ __launch_bounds__(512, 2)
void gemm_ff1(const u16* __restrict__ A, const u16* __restrict__ Bt,
              u16* __restrict__ C, const float* __restrict__ bias)
{
    __shared__ alignas(16) u16 As[2][256 * 64];
    __shared__ alignas(16) u16 Bs[2][256 * 64];
    const int m0 = blockIdx.x * 256, n0 = blockIdx.y * 256;
    const int t = threadIdx.x, lane = t & 63, w = t >> 6;
    const int wm = (w >> 2) * 128, wn = (w & 3) * 64;   // wave origin
    const int fr = lane & 15, fq = lane >> 4;
    f32x4 acc[8][4] = {};                                // 8 m-frags x 4 n-frags

    // staging: 512 threads x 16B = 8KB/pass = 64 rows x 64 cols, swizzled src
    const int r0a = t >> 3;                              // 0..63
    const int c0sw = ((t & 7) ^ (r0a & 7)) * 8;
    auto stA = [&](u16* dst, int k0, int p) {
        gll16(A + (long)(m0 + p * 64 + r0a) * 1024 + k0 + c0sw,
              dst + p * 4096 + w * 512);
    };
    auto stB = [&](u16* dst, int k0, int p) {
        gll16(Bt + (long)(n0 + p * 64 + r0a) * 1024 + k0 + c0sw,
              dst + p * 4096 + w * 512);
    };

    // prologue: stage K-step 0 fully
#pragma unroll
    for (int p = 0; p < 4; p++) { stA(As[0], 0, p); stB(Bs[0], 0, p); }
    __syncthreads();
    int cur = 0;
    for (int k0 = 0; k0 < 1024; k0 += 64) {
        const u16* as = As[cur]; const u16* bs = Bs[cur];
        u16* an = As[cur ^ 1];  u16* bn = Bs[cur ^ 1];
        const bool pre = (k0 + 64 < 1024);
        const int kn = k0 + 64;
        bf16x8 af[4][2], bfv[4][2];

        // ---- phase 0: stage next-A (all 4 passes); read A(mq0)+B(nf0,1)
        if (pre) { stA(an, kn, 0); stA(an, kn, 1); stA(an, kn, 2); stA(an, kn, 3); }
#pragma unroll
        for (int mf = 0; mf < 4; mf++)
#pragma unroll
            for (int kk = 0; kk < 2; kk++) {
                const int row = wm + mf * 16 + fr;
                af[mf][kk] = ld8(&as[row * 64 + (((kk * 4 + fq) ^ (row & 7)) << 3)]);
            }
#pragma unroll
        for (int nf = 0; nf < 2; nf++)
#pragma unroll
            for (int kk = 0; kk < 2; kk++) {
                const int row = wn + nf * 16 + fr;
                bfv[nf][kk] = ld8(&bs[row * 64 + (((kk * 4 + fq) ^ (row & 7)) << 3)]);
            }
        __builtin_amdgcn_s_setprio(1);
#pragma unroll
        for (int mf = 0; mf < 4; mf++)
#pragma unroll
            for (int nf = 0; nf < 2; nf++)
#pragma unroll
                for (int kk = 0; kk < 2; kk++)
                    acc[mf][nf] = __builtin_amdgcn_mfma_f32_16x16x32_bf16(af[mf][kk], bfv[nf][kk], acc[mf][nf], 0, 0, 0);
        __builtin_amdgcn_s_setprio(0);

        // ---- phase 1: stage next-B (all 4 passes); read B(nf2,3)
        if (pre) { stB(bn, kn, 0); stB(bn, kn, 1); stB(bn, kn, 2); stB(bn, kn, 3); }
#pragma unroll
        for (int nf = 2; nf < 4; nf++)
#pragma unroll
            for (int kk = 0; kk < 2; kk++) {
                const int row = wn + nf * 16 + fr;
                bfv[nf][kk] = ld8(&bs[row * 64 + (((kk * 4 + fq) ^ (row & 7)) << 3)]);
            }
        __builtin_amdgcn_s_setprio(1);
#pragma unroll
        for (int mf = 0; mf < 4; mf++)
#pragma unroll
            for (int nf = 2; nf < 4; nf++)
#pragma unroll
                for (int kk = 0; kk < 2; kk++)
                    acc[mf][nf] = __builtin_amdgcn_mfma_f32_16x16x32_bf16(af[mf][kk], bfv[nf][kk], acc[mf][nf], 0, 0, 0);
        __builtin_amdgcn_s_setprio(0);

        // ---- phase 2: read A(mq1) (overwrites af); mma (mq1, nf0,1)
#pragma unroll
        for (int mf = 0; mf < 4; mf++)
#pragma unroll
            for (int kk = 0; kk < 2; kk++) {
                const int row = wm + 64 + mf * 16 + fr;
                af[mf][kk] = ld8(&as[row * 64 + (((kk * 4 + fq) ^ (row & 7)) << 3)]);
            }
        __builtin_amdgcn_s_setprio(1);
#pragma unroll
        for (int mf = 0; mf < 4; mf++)
#pragma unroll
            for (int nf = 0; nf < 2; nf++)
#pragma unroll
                for (int kk = 0; kk < 2; kk++)
                    acc[4 + mf][nf] = __builtin_amdgcn_mfma_f32_16x16x32_bf16(af[mf][kk], bfv[nf][kk], acc[4 + mf][nf], 0, 0, 0);
        __builtin_amdgcn_s_setprio(0);

        // ---- phase 3: mma (mq1, nf2,3)
        __builtin_amdgcn_s_setprio(1);
#pragma unroll
        for (int mf = 0; mf < 4; mf++)
#pragma unroll
            for (int nf = 2; nf < 4; nf++)
#pragma unroll
                for (int kk = 0; kk < 2; kk++)
                    acc[4 + mf][nf] = __builtin_amdgcn_mfma_f32_16x16x32_bf16(af[mf][kk], bfv[nf][kk], acc[4 + mf][nf], 0, 0, 0);
        __builtin_amdgcn_s_setprio(0);

        __syncthreads();                 // drains vmcnt (cheap: issued P0/P1)
        cur ^= 1;
    }

    // epilogue: bias + gelu + bf16 store (ldc = 4096)
#pragma unroll
    for (int nf = 0; nf < 4; nf++) {
        const int col = n0 + wn + nf * 16 + fr;
        const float bv = bias[col];
#pragma unroll
        for (int mf = 0; mf < 8; mf++) {
            const int rbase = m0 + wm + mf * 16 + fq * 4;
#pragma unroll
            for (int r = 0; r < 4; r++) {
                float v = gelu_f(acc[mf][nf][r] + bv);
                C[(long)(rbase + r) * 4096 + col] = f2bf(v);
            }
        }
    }
}

// ---------------------------------------------------------------------------
// Merged q|k|vT|vcT dispatch: 1024 blocks of 128x128, K=1024, BK=32, 4/CU.
// ---------------------------------------------------------------------------
__global__ __launch_bounds__(256, 4)
void gemm_qkv4(const u16* __restrict__ xB,  const u16* __restrict__ Wq,
               const u16* __restrict__ Wk,  u16* __restrict__ qB,
               u16* __restrict__ kB,
               const u16* __restrict__ Wv,  const u16* __restrict__ Wvc,
               const u16* __restrict__ encB,
               u16* __restrict__ vTB, u16* __restrict__ vcTB)
{
    const long M1 = (long)N_ * D_;
    int bid = blockIdx.x;
    const u16* A; const u16* Bt; u16* C; int m0, n0;
    if (bid < 512) {
        int bx = bid & 31, by = bid >> 5;
        A = xB; m0 = bx * 128;
        if (by < 8) { Bt = Wq; C = qB; n0 = by * 128; }
        else        { Bt = Wk; C = kB; n0 = (by - 8) * 128; }
    } else {
        int sub = bid - 512;
        int bx = sub & 7, by = (sub >> 3) & 7, bz = sub >> 6;
        m0 = bx * 128; n0 = by * 128;
        if (bz < 4) { A = Wv;  Bt = xB   + (long)bz * M1;       C = vTB  + (long)bz * M1; }
        else        { A = Wvc; Bt = encB + (long)(bz - 4) * M1; C = vcTB + (long)(bz - 4) * M1; }
    }
    gemm_body<128, 128, 32, 0, 0, 0>(
        A, Bt, (char*)C, nullptr, 1.f, 1024, 1024, 1024, 1024, m0, n0);
}

// ---------------------------------------------------------------------------
// 32x32-tile transpose with cast to bf16 (restored for kcT).
// ---------------------------------------------------------------------------
template<int INF32>
__global__ __launch_bounds__(256)
void transpose_cast(const void* __restrict__ in, u16* __restrict__ out,
                    int R, int C, long sIn, long sOut)
{
    __shared__ u16 tile[32][33];
    const char* ip = (const char*)in + (long)blockIdx.z * sIn * (INF32 ? 4 : 2);
    u16*        op = out + (long)blockIdx.z * sOut;
    const int bx = blockIdx.x * 32, by = blockIdx.y * 32;
    const int tx = threadIdx.x & 31, ty = threadIdx.x >> 5;
#pragma unroll
    for (int i = ty; i < 32; i += 8) {
        long idx = (long)(by + i) * C + bx + tx;
        tile[i][tx] = INF32 ? f2bf(((const float*)ip)[idx]) : ((const u16*)ip)[idx];
    }
    __syncthreads();
#pragma unroll
    for (int i = ty; i < 32; i += 8) op[(long)(bx + i) * R + by + tx] = tile[tx][i];
}

// ---------------------------------------------------------------------------
// w1 [1024,4096] and w2 [4096,1024] transposes fused: grid (128, 32, 2).
// ---------------------------------------------------------------------------
__global__ __launch_bounds__(256)
void transpose_ff(const float* __restrict__ w1, const float* __restrict__ w2,
                  u16* __restrict__ o1, u16* __restrict__ o2)
{
    __shared__ u16 tile[32][33];
    const float* in; u16* out; int R, C, bx, by;
    if (blockIdx.z == 0) {
        in = w1; out = o1; R = 1024; C = 4096;
        bx = blockIdx.x; by = blockIdx.y;                 // bx<128, by<32
    } else {
        in = w2; out = o2; R = 4096; C = 1024;
        bx = blockIdx.x >> 2; by = blockIdx.y * 4 + (blockIdx.x & 3);  // bx<32, by<128
    }
    const int x0 = bx * 32, y0 = by * 32;
    const int tx = threadIdx.x & 31, ty = threadIdx.x >> 5;
#pragma unroll
    for (int i = ty; i < 32; i += 8)
        tile[i][tx] = f2bf(in[(long)(y0 + i) * C + x0 + tx]);
    __syncthreads();
#pragma unroll
    for (int i = ty; i < 32; i += 8)
        out[(long)(x0 + i) * R + y0 + tx] = tile[tx][i];
}

// ---------------------------------------------------------------------------
// Row softmax: 1024 fp32 in -> 1024 bf16 out; one wave per row.
// ---------------------------------------------------------------------------
__global__ __launch_bounds__(256)
void softmax_1024(const float* __restrict__ in, u16* __restrict__ out)
{
    const int lane = threadIdx.x & 63, wv = threadIdx.x >> 6;
    const long row = (long)blockIdx.x * 4 + wv;
    const float* p = in + row * 1024 + lane * 16;
    float v[16];
#pragma unroll
    for (int q = 0; q < 4; q++) {
        f32x4 a = *(const f32x4*)(p + q * 4);
#pragma unroll
        for (int e = 0; e < 4; e++) v[q * 4 + e] = a[e];
    }
    float mx = v[0];
#pragma unroll
    for (int i = 1; i < 16; i++) mx = fmaxf(mx, v[i]);
#pragma unroll
    for (int off = 32; off; off >>= 1) mx = fmaxf(mx, __shfl_xor(mx, off, 64));
    float s = 0.f;
#pragma unroll
    for (int i = 0; i < 16; i++) { v[i] = __expf(v[i] - mx); s += v[i]; }
#pragma unroll
    for (int off = 32; off; off >>= 1) s += __shfl_xor(s, off, 64);
    const float inv = 1.0f / s;
    u16* qp = out + row * 1024 + lane * 16;
#pragma unroll
    for (int q = 0; q < 2; q++) {
        u16x8 o;
#pragma unroll
        for (int e = 0; e < 8; e++) o[e] = f2bf(v[q * 8 + e] * inv);
        *(u16x8*)(qp + q * 8) = o;
    }
}

// ---------------------------------------------------------------------------
// out = LayerNorm(a (+a2) (+bb) + res) * g + beta ; rows of 1024; 1 wave/row.
// ---------------------------------------------------------------------------
template<int AF32, int RESF32, int OUTF32, int ADDB, int A2>
__global__ __launch_bounds__(256)
void ln_res(const void* __restrict__ Av, const void* __restrict__ Rv,
            const float* __restrict__ g, const float* __restrict__ be,
            void* __restrict__ out, const float* __restrict__ bb,
            const u16* __restrict__ Av2)
{
    const int lane = threadIdx.x & 63, wv = threadIdx.x >> 6;
    const long row = (long)blockIdx.x * 4 + wv;
    const long off = row * 1024 + lane * 16;
    const int c0 = lane * 16;
    float v[16];
    if (AF32) {
#pragma unroll
        for (int q = 0; q < 4; q++) {
            f32x4 a = *((const f32x4*)((const float*)Av + off) + q);
#pragma unroll
            for (int e = 0; e < 4; e++) v[q * 4 + e] = a[e];
        }
    } else {
#pragma unroll
        for (int q = 0; q < 2; q++) {
            u16x8 a = *((const u16x8*)((const u16*)Av + off) + q);
#pragma unroll
            for (int e = 0; e < 8; e++) v[q * 8 + e] = bf2f(a[e]);
        }
    }
    if (A2) {
#pragma unroll
        for (int q = 0; q < 2; q++) {
            u16x8 a = *((const u16x8*)(Av2 + off) + q);
#pragma unroll
            for (int e = 0; e < 8; e++) v[q * 8 + e] += bf2f(a[e]);
        }
    }
    if (ADDB) {
#pragma unroll
        for (int q = 0; q < 4; q++) {
            f32x4 a = *(const f32x4*)&bb[c0 + q * 4];
#pragma unroll
            for (int e = 0; e < 4; e++) v[q * 4 + e] += a[e];
        }
    }
    if (RESF32) {
#pragma unroll
        for (int q = 0; q < 4; q++) {
            f32x4 a = *((const f32x4*)((const float*)Rv + off) + q);
#pragma unroll
            for (int e = 0; e < 4; e++) v[q * 4 + e] += a[e];
        }
    } else {
#pragma unroll
        for (int q = 0; q < 2; q++) {
            u16x8 a = *((const u16x8*)((const u16*)Rv + off) + q);
#pragma unroll
            for (int e = 0; e < 8; e++) v[q * 8 + e] += bf2f(a[e]);
        }
    }
    float s = 0.f;
#pragma unroll
    for (int i = 0; i < 16; i++) s += v[i];
#pragma unroll
    for (int o = 32; o; o >>= 1) s += __shfl_xor(s, o, 64);
    const float mu = s * (1.f / 1024.f);
    float s2 = 0.f;
#pragma unroll
    for (int i = 0; i < 16; i++) { float d = v[i] - mu; s2 += d * d; }
#pragma unroll
    for (int o = 32; o; o >>= 1) s2 += __shfl_xor(s2, o, 64);
    const float rs = rsqrtf(s2 * (1.f / 1024.f) + 1e-5f);

    float ov[16];
#pragma unroll
    for (int q = 0; q < 4; q++) {
        f32x4 gv = *(const f32x4*)&g[c0 + q * 4];
        f32x4 bv = *(const f32x4*)&be[c0 + q * 4];
#pragma unroll
        for (int e = 0; e < 4; e++)
            ov[q * 4 + e] = (v[q * 4 + e] - mu) * rs * gv[e] + bv[e];
    }
    if (OUTF32) {
#pragma unroll
        for (int q = 0; q < 4; q++) {
            f32x4 o;
#pragma unroll
            for (int e = 0; e < 4; e++) o[e] = ov[q * 4 + e];
            *((f32x4*)((float*)out + off) + q) = o;
        }
    } else {
#pragma unroll
        for (int q = 0; q < 2; q++) {
            u16x8 o;
#pragma unroll
            for (int e = 0; e < 8; e++) o[e] = f2bf(ov[q * 8 + e]);
            *((u16x8*)((u16*)out + off) + q) = o;
        }
    }
}

// ---------------------------------------------------------------------------
// Flash cross-attention. Grid: (8 i-tiles, 16 heads, 4 b). T5 setprio.
// ---------------------------------------------------------------------------
__global__ __launch_bounds__(256, 3)
void flash_ca(const u16* __restrict__ P, const u16* __restrict__ Kc,
              const u16* __restrict__ VT, u16* __restrict__ O)
{
    __shared__ alignas(16) u16 Ks[2][64 * 64];
    __shared__ alignas(16) u16 Vs[2][64 * 64];   // [d][j]
    __shared__ alignas(16) u16 Ps[128 * 72];     // per-wave 32-row strips
    const int b = blockIdx.z, h = blockIdx.y, it = blockIdx.x;
    const long base = (long)b * N_ * D_;
    const int t = threadIdx.x, lane = t & 63, w = t >> 6;
    const int fr = lane & 15, fq = lane >> 4;

    bf16x8 qf[2][2];
#pragma unroll
    for (int mt = 0; mt < 2; mt++)
#pragma unroll
        for (int hf = 0; hf < 2; hf++)
            qf[mt][hf] = ld8(&P[base + (long)(it * 128 + w * 32 + mt * 16 + fr) * D_
                                + h * 64 + hf * 32 + fq * 8]);

    // staging: thread t -> row (t>>3), dest slot (t&7); global chunk = slot ^ (row&7)
    const int svr = t >> 3, svc = ((t & 7) ^ (svr & 7)) * 8;
    auto stageK = [&](int buf, int jt) {
#pragma unroll
        for (int p = 0; p < 2; p++)
            gll16(Kc + base + (long)(jt * 64 + p * 32 + svr) * D_ + h * 64 + svc,
                  &Ks[buf][p * 2048 + w * 512]);
    };
    auto stageV = [&](int buf, int jt) {
#pragma unroll
        for (int p = 0; p < 2; p++)
            gll16(VT + base + (long)(h * 64 + p * 32 + svr) * D_ + jt * 64 + svc,
                  &Vs[buf][p * 2048 + w * 512]);
    };

    f32x4 o[2][4] = {};
    float l_lane[2][4] = {};

    stageK(0, 0); stageV(0, 0);
    int cur = 0;
    for (int jt = 0; jt < 16; jt++) {
        __syncthreads();
        if (jt + 1 < 16) { stageK(cur ^ 1, jt + 1); stageV(cur ^ 1, jt + 1); }
        const u16* ks = Ks[cur];
        const u16* vs = Vs[cur];

        f32x4 st[2][4] = {};
        __builtin_amdgcn_s_setprio(1);
#pragma unroll
        for (int nt = 0; nt < 4; nt++) {
            const int row = nt * 16 + fr;
            bf16x8 b0 = ld8(&ks[row * 64 + ((fq ^ (row & 7)) << 3)]);
            bf16x8 b1 = ld8(&ks[row * 64 + (((fq + 4) ^ (row & 7)) << 3)]);
#pragma unroll
            for (int mt = 0; mt < 2; mt++) {
                st[mt][nt] = __builtin_amdgcn_mfma_f32_16x16x32_bf16(qf[mt][0], b0, st[mt][nt], 0, 0, 0);
                st[mt][nt] = __builtin_amdgcn_mfma_f32_16x16x32_bf16(qf[mt][1], b1, st[mt][nt], 0, 0, 0);
            }
        }
        __builtin_amdgcn_s_setprio(0);
#pragma unroll
        for (int mt = 0; mt < 2; mt++)
#pragma unroll
            for (int nt = 0; nt < 4; nt++)
#pragma unroll
                for (int r = 0; r < 4; r++) {
                    float e = __expf(st[mt][nt][r]);
                    l_lane[mt][r] += e;
                    Ps[(w * 32 + mt * 16 + fq * 4 + r) * 72 + nt * 16 + fr] = f2bf(e);
                }
        __asm__ volatile("s_waitcnt lgkmcnt(0)" ::: "memory");
        bf16x8 vf[4][2];
#pragma unroll
        for (int dt = 0; dt < 4; dt++) {
            const int row = dt * 16 + fr;
            vf[dt][0] = ld8(&vs[row * 64 + ((fq ^ (row & 7)) << 3)]);
            vf[dt][1] = ld8(&vs[row * 64 + (((fq + 4) ^ (row & 7)) << 3)]);
        }
        __builtin_amdgcn_s_setprio(1);
#pragma unroll
        for (int mt = 0; mt < 2; mt++) {
            bf16x8 p0 = ld8(&Ps[(w * 32 + mt * 16 + fr) * 72 + fq * 8]);
            bf16x8 p1 = ld8(&Ps[(w * 32 + mt * 16 + fr) * 72 + 32 + fq * 8]);
#pragma unroll
            for (int dt = 0; dt < 4; dt++) {
                o[mt][dt] = __builtin_amdgcn_mfma_f32_16x16x32_bf16(p0, vf[dt][0], o[mt][dt], 0, 0, 0);
                o[mt][dt] = __builtin_amdgcn_mfma_f32_16x16x32_bf16(p1, vf[dt][1], o[mt][dt], 0, 0, 0);
            }
        }
        __builtin_amdgcn_s_setprio(0);
        cur ^= 1;
    }
#pragma unroll
    for (int mt = 0; mt < 2; mt++)
#pragma unroll
        for (int r = 0; r < 4; r++) {
            float lt = l_lane[mt][r];
#pragma unroll
            for (int off = 1; off < 16; off <<= 1) lt += __shfl_xor(lt, off, 64);
            l_lane[mt][r] = 1.0f / lt;
        }
#pragma unroll
    for (int mt = 0; mt < 2; mt++)
#pragma unroll
        for (int dt = 0; dt < 4; dt++)
#pragma unroll
            for (int r = 0; r < 4; r++)
                O[base + (long)(it * 128 + w * 32 + mt * 16 + fq * 4 + r) * D_
                  + h * 64 + dt * 16 + fr] = f2bf(o[mt][dt][r] * l_lane[mt][r]);
}

// ---------------------------------------------------------------------------
extern "C" void kernel_launch(void* const* d_in, const int* in_sizes, int n_in,
                              void* d_out, int out_size, void* d_ws, size_t ws_size,
                              hipStream_t stream)
{
    const float* x     = (const float*)d_in[0];
    const float* enc   = (const float*)d_in[1];
    const float* sa_wq = (const float*)d_in[2];
    const float* sa_wk = (const float*)d_in[3];
    const float* sa_wv = (const float*)d_in[4];
    const float* sa_g  = (const float*)d_in[5];
    const float* sa_b  = (const float*)d_in[6];
    const float* ca_wq = (const float*)d_in[7];
    const float* ca_wk = (const float*)d_in[8];
    const float* ca_wv = (const float*)d_in[9];
    const float* ca_g  = (const float*)d_in[10];
    const float* ca_b  = (const float*)d_in[11];
    const float* w1    = (const float*)d_in[12];
    const float* b1    = (const float*)d_in[13];
    const float* w2    = (const float*)d_in[14];
    const float* b2    = (const float*)d_in[15];
    const float* ff_g  = (const float*)d_in[16];
    const float* ff_b  = (const float*)d_in[17];

    // 76 MB workspace, lifetime-overlaid (MB offsets):
    //  0- 8 xB -> attnB(attn->P) -> w2T
    //  8-16 encB -> w1T
    // 16-22 Wsa ; 22-28 Wca ; 16-32 h2P[2] (bf16 split-K partials, FF phase)
    // 28-36 qB_sa -> E(saln) -> flash O
    // 36-44 kB_sa -> qB(ca) -> calnB
    // 44-52 vTB -> kB(ca) ; 44-76 h1B (FF)
    // 52-60 vcTB
    // 60-76 scF (fp32) ; 60-68 kcT (CA)
    char* ws = (char*)d_ws;
    const size_t MB = 1ull << 20;
    u16*  xB    = (u16*)(ws + 0 * MB);
    u16*  attnB = (u16*)(ws + 0 * MB);
    u16*  w2T   = (u16*)(ws + 0 * MB);
    u16*  encB  = (u16*)(ws + 8 * MB);
    u16*  w1T   = (u16*)(ws + 8 * MB);
    u16*  Wsa   = (u16*)(ws + 16 * MB);   // q@+0, k@+1M, v@+2M elems
    u16*  Wca   = (u16*)(ws + 22 * MB);
    u16*  h2P   = (u16*)(ws + 16 * MB);   // split-K partials: p0, p1 (8MB each)
    u16*  qBsa  = (u16*)(ws + 28 * MB);
    u16*  E     = (u16*)(ws + 28 * MB);   // saln, then flash O
    u16*  kBsa  = (u16*)(ws + 36 * MB);
    u16*  qBca  = (u16*)(ws + 36 * MB);
    u16*  calnB = (u16*)(ws + 36 * MB);
    u16*  vTB   = (u16*)(ws + 44 * MB);
    u16*  kBca  = (u16*)(ws + 44 * MB);
    u16*  h1B   = (u16*)(ws + 44 * MB);
    u16*  vcTB  = (u16*)(ws + 52 * MB);
    float* scF  = (float*)(ws + 60 * MB);
    u16*  kcT   = (u16*)(ws + 60 * MB);

    const dim3 blk(256, 1, 1);
    const long M1 = (long)N_ * D_;        // 1M elems, per-batch stride
    const long W1M = (long)1024 * 1024;   // weight matrix elems

    // 0) fused prep: x|enc converts + six weight transposes (one dispatch)
    prep_all<<<dim3(10240, 1, 1), blk, 0, stream>>>(
        x, enc, xB, encB, sa_wq, sa_wk, sa_wv, ca_wq, ca_wk, ca_wv, Wsa, Wca);

    // 2) q|k|vT|vcT merged: 1024 blocks of 128x128, 4 blocks/CU.
    gemm_qkv4<<<dim3(1024, 1, 1), blk, 0, stream>>>(
        xB, Wsa, Wsa + W1M, qBsa, kBsa,
        Wsa + 2 * W1M, Wca + 2 * W1M, encB, vTB, vcTB);
    // 4) scores = q k^T / 32 (fp32). grid 8x16x4 = 512, 128x64, BK=64.
    gemm_a<128,64,64,0,1,0,0><<<dim3(8, 16, 4), blk, 0, stream>>>(
        qBsa, nullptr, kBsa, nullptr, scF, nullptr, nullptr,
        0.03125f, 1024, 1024, 1024, 1024, M1, M1, M1);
    softmax_1024<<<dim3(1024, 1, 1), blk, 0, stream>>>(scF, attnB);
    // 5) sa_pre = attn @ v (fp32), BK=64
    gemm_a<128,64,64,0,1,0,0><<<dim3(8, 16, 4), blk, 0, stream>>>(
        attnB, nullptr, vTB, nullptr, scF, nullptr, nullptr,
        1.f, 1024, 1024, 1024, 1024, M1, M1, M1);
    ln_res<1,1,0,0,0><<<dim3(1024, 1, 1), blk, 0, stream>>>(
        scF, x, sa_g, sa_b, E, nullptr, nullptr);

    // 6) qc|kc fused (y-half): qc = saln @ Wq ; kc = encB @ Wk. BK=64.
    gemm_a<128,128,64,1,0,0,0><<<dim3(32, 16, 1), blk, 0, stream>>>(
        E, encB, Wca, Wca + W1M, qBca, kBca, nullptr,
        1.f, 1024, 1024, 1024, 1024, 0, 0, 0);
    // 7) kcT per batch (restored dispatch; scatter fusion measured +9us)
    transpose_cast<0><<<dim3(32, 32, 4), blk, 0, stream>>>(kBca, kcT, 1024, 1024, M1, M1);
    // 8) P = (qc @ kc) / 64, BK=64
    gemm_a<128,64,64,0,0,0,0><<<dim3(8, 16, 4), blk, 0, stream>>>(
        qBca, nullptr, kcT, nullptr, attnB, nullptr, nullptr,
        0.015625f, 1024, 1024, 1024, 1024, M1, M1, M1);
    // 9) flash cross-attn -> O (over saln region)
    flash_ca<<<dim3(8, 16, 4), blk, 0, stream>>>(attnB, kBca, vcTB, E);
    ln_res<0,1,0,0,0><<<dim3(1024, 1, 1), blk, 0, stream>>>(
        E, enc, ca_g, ca_b, calnB, nullptr, nullptr);

    // 10) FeedForward.
    transpose_ff<<<dim3(128, 32, 2), blk, 0, stream>>>(w1, w2, w1T, w2T);
    // FF1: 256^2-tile 8-wave structural kernel, 256 blocks = 1/CU.
    gemm_ff1<<<dim3(16, 16, 1), dim3(512, 1, 1), 0, stream>>>(
        calnB, w1T, h1B, b1);
    // FF2 split-K=2, DIRECT bf16 stores (measured -3.3us vs single-K).
    gemm_a<128,128,32,0,0,0,0><<<dim3(32, 8, 2), blk, 0, stream>>>(
        h1B, nullptr, w2T, nullptr, h2P, nullptr, nullptr,
        1.f, 2048, 4096, 4096, 1024, 2048, 2048, 4194304);
    // final LN folds p0 + p1 (A2) + b2 (ADDB) + residual calnB.
    ln_res<0,0,1,1,1><<<dim3(1024, 1, 1), blk, 0, stream>>>(
        h2P, calnB, ff_g, ff_b, (float*)d_out, b2, h2P + 4194304);
}